// Round 3
// baseline (6041.919 us; speedup 1.0000x reference)
//
#include <hip/hip_runtime.h>

using bf16 = __bf16;
typedef bf16 bf16x8 __attribute__((ext_vector_type(8)));
typedef float f32x4 __attribute__((ext_vector_type(4)));

#define MFMA16(a, b, c) __builtin_amdgcn_mfma_f32_16x16x32_bf16(a, b, c, 0, 0, 0)

// ---------------- helpers ----------------

__device__ __forceinline__ bf16x8 to_bf16x8(float4 a, float4 b) {
    bf16x8 v;
    v[0] = (bf16)a.x; v[1] = (bf16)a.y; v[2] = (bf16)a.z; v[3] = (bf16)a.w;
    v[4] = (bf16)b.x; v[5] = (bf16)b.y; v[6] = (bf16)b.z; v[7] = (bf16)b.w;
    return v;
}

// A-fragment from a swizzled row-major LDS tile [rows][ldK] bf16.
// Swizzle: byte_off_in_row ^= ((row&7)<<4). Requires ldK*2 % 128 == 0.
__device__ __forceinline__ bf16x8 lds_afrag(const char* smem, int ldK, int mbase, int kbase, int lane) {
    int r = mbase + (lane & 15);
    int off = (kbase + ((lane >> 4) << 3)) << 1;
    off ^= (r & 7) << 4;
    return *(const bf16x8*)(smem + r * (ldK << 1) + off);
}

// B-fragment from global WT[N][K] bf16 (i.e., W transposed): 8 contiguous k at row n.
__device__ __forceinline__ bf16x8 glb_bfrag(const bf16* __restrict__ WT, int K, int nbase, int kbase, int lane) {
    int n = nbase + (lane & 15);
    int k = kbase + ((lane >> 4) << 3);
    return *(const bf16x8*)(WT + (size_t)n * K + k);
}

// ---------------- small kernels ----------------

__global__ void k_transpose(const float* __restrict__ W, bf16* __restrict__ WT,
                            int K, int N, int ldT, int k0) {
    int idx = blockIdx.x * 256 + threadIdx.x;
    if (idx < K * N) {
        int k = idx / N, n = idx - k * N;
        WT[(size_t)n * ldT + k0 + k] = (bf16)W[idx];
    }
}

__global__ void k_deg(const int* __restrict__ dst, float* __restrict__ deg, int E) {
    int e = blockIdx.x * 256 + threadIdx.x;
    if (e < E) atomicAdd(&deg[dst[e]], 1.0f);
}

__global__ void k_scan(const float* __restrict__ deg, unsigned* __restrict__ offsets,
                       float* __restrict__ invdeg, int N) {
    __shared__ unsigned wsum[16];
    __shared__ unsigned carry_s, tot_s;
    const int tid = threadIdx.x, lane = tid & 63, wid = tid >> 6;
    if (tid == 0) carry_s = 0;
    __syncthreads();
    for (int base = 0; base < N; base += 1024) {
        int i = base + tid;
        unsigned v = (i < N) ? (unsigned)deg[i] : 0u;
        unsigned inc = v;
        #pragma unroll
        for (int d = 1; d < 64; d <<= 1) {
            unsigned t = (unsigned)__shfl_up((int)inc, d, 64);
            if (lane >= d) inc += t;
        }
        if (lane == 63) wsum[wid] = inc;
        __syncthreads();
        if (wid == 0) {
            unsigned wv = (lane < 16) ? wsum[lane] : 0u;
            unsigned winc = wv;
            #pragma unroll
            for (int d = 1; d < 16; d <<= 1) {
                unsigned t = (unsigned)__shfl_up((int)winc, d, 16);
                if ((lane & 15) >= d) winc += t;
            }
            if (lane < 16) wsum[lane] = winc - wv;
            if (lane == 15) tot_s = winc;
        }
        __syncthreads();
        if (i < N) {
            offsets[i] = carry_s + wsum[wid] + (inc - v);
            invdeg[i] = 1.0f / fmaxf(deg[i], 1.0f);
        }
        __syncthreads();
        if (tid == 0) carry_s += tot_s;
        __syncthreads();
    }
    if (tid == 0) offsets[N] = carry_s;
}

__global__ void k_scatter(const int* __restrict__ dst, const unsigned* __restrict__ offsets,
                          unsigned* __restrict__ cursor, unsigned* __restrict__ eid, int E) {
    int e = blockIdx.x * 256 + threadIdx.x;
    if (e < E) {
        int d = dst[e];
        unsigned p = atomicAdd(&cursor[d], 1u);
        eid[offsets[d] + p] = (unsigned)e;
    }
}

__global__ __launch_bounds__(256)
void k_agg(const float* __restrict__ xin, const float* __restrict__ ef, const int* __restrict__ src,
           const unsigned* __restrict__ offsets, const float* __restrict__ invdeg,
           const unsigned* __restrict__ eid, float* __restrict__ sm, int N) {
    const int lane = threadIdx.x & 63, w = threadIdx.x >> 6;
    int nb = blockIdx.x * 16 + w * 4;
    for (int j = 0; j < 4; ++j) {
        int n = nb + j;
        if (n >= N) return;
        unsigned o0 = offsets[n], o1 = offsets[n + 1];
        float s0 = 0.f, s1 = 0.f, s2 = 0.f;
        for (unsigned t = o0; t < o1; ++t) {
            int e = (int)eid[t];
            int v = src[e];
            s0 += xin[(size_t)v * 128 + lane];
            s1 += xin[(size_t)v * 128 + 64 + lane];
            s2 += ef[(size_t)e * 64 + lane];
        }
        float g = invdeg[n];
        sm[(size_t)n * 192 + lane] = s0 * g;
        sm[(size_t)n * 192 + 64 + lane] = s1 * g;
        sm[(size_t)n * 192 + 128 + lane] = s2 * g;
    }
}

__global__ __launch_bounds__(256)
void k_nodegemm(const float* __restrict__ xin, const float* __restrict__ sm,
                const bf16* __restrict__ WcatT,
                const float* __restrict__ b_self, const float* __restrict__ b_nb,
                const unsigned* __restrict__ offsets,
                float* __restrict__ xout, int N) {
    __shared__ char smem[64 * 320 * 2];
    const int tid = threadIdx.x, lane = tid & 63, w = tid >> 6;
    const int n0 = blockIdx.x * 64;
    for (int it = tid; it < 64 * 40; it += 256) {
        int r = it / 40, c = it - r * 40;
        int node = n0 + r;
        float4 fa = {0, 0, 0, 0}, fb = {0, 0, 0, 0};
        if (node < N) {
            int base = c * 8;
            const float* p = (base < 128) ? xin + (size_t)node * 128 + base
                                          : sm + (size_t)node * 192 + (base - 128);
            fa = *(const float4*)p;
            fb = *(const float4*)(p + 4);
        }
        bf16x8 v = to_bf16x8(fa, fb);
        *(bf16x8*)(smem + r * 640 + ((c * 16) ^ ((r & 7) << 4))) = v;
    }
    __syncthreads();

    f32x4 acc[4][2];
    #pragma unroll
    for (int m = 0; m < 4; ++m)
        #pragma unroll
        for (int n = 0; n < 2; ++n) acc[m][n] = (f32x4){0.f, 0.f, 0.f, 0.f};

    for (int ks = 0; ks < 10; ++ks) {
        bf16x8 a[4];
        #pragma unroll
        for (int m = 0; m < 4; ++m) a[m] = lds_afrag(smem, 320, m * 16, ks * 32, lane);
        #pragma unroll
        for (int n = 0; n < 2; ++n) {
            bf16x8 b = glb_bfrag(WcatT, 320, w * 32 + n * 16, ks * 32, lane);
            #pragma unroll
            for (int m = 0; m < 4; ++m) acc[m][n] = MFMA16(a[m], b, acc[m][n]);
        }
    }

    #pragma unroll
    for (int n = 0; n < 2; ++n) {
        int col = w * 32 + n * 16 + (lane & 15);
        float bs = b_self[col], bn = b_nb[col];
        #pragma unroll
        for (int m = 0; m < 4; ++m)
            #pragma unroll
            for (int rr = 0; rr < 4; ++rr) {
                int row = m * 16 + ((lane >> 4) << 2) + rr;
                int node = n0 + row;
                if (node < N) {
                    bool hd = offsets[node + 1] > offsets[node];
                    xout[(size_t)node * 128 + col] =
                        fmaxf(acc[m][n][rr] + bs + (hd ? bn : 0.f), 0.f);
                }
            }
    }
}

__global__ void k_finalize(const float* __restrict__ sum, const float* __restrict__ sq,
                           const float* __restrict__ g, const float* __restrict__ beta,
                           float* __restrict__ scale, float* __restrict__ shift,
                           int n, float invE) {
    int i = blockIdx.x * 256 + threadIdx.x;
    if (i < n) {
        float m = sum[i] * invE;
        float v = sq[i] * invE - m * m;
        float sc = g[i] * rsqrtf(v + 1e-5f);
        scale[i] = sc;
        shift[i] = beta[i] - m * sc;
    }
}

// ---------------- shared MLP building blocks ----------------

__device__ __forceinline__ void run_gemm1(const char* smem, const bf16* __restrict__ W1T,
                                          int w, int lane, f32x4 (&acc)[4][8]) {
    #pragma unroll
    for (int m = 0; m < 4; ++m)
        #pragma unroll
        for (int n = 0; n < 8; ++n) acc[m][n] = (f32x4){0.f, 0.f, 0.f, 0.f};
    #pragma unroll 2
    for (int ks = 0; ks < 10; ++ks) {
        bf16x8 a[4];
        #pragma unroll
        for (int m = 0; m < 4; ++m) a[m] = lds_afrag(smem, 320, m * 16, ks * 32, lane);
        #pragma unroll
        for (int n = 0; n < 8; ++n) {
            bf16x8 b = glb_bfrag(W1T, 320, w * 128 + n * 16, ks * 32, lane);
            #pragma unroll
            for (int m = 0; m < 4; ++m) acc[m][n] = MFMA16(a[m], b, acc[m][n]);
        }
    }
}

__device__ __forceinline__ void stage_pair_glb(char* smem, const bf16* __restrict__ pairG,
                                               int e0, int tid) {
    for (int it = tid; it < 64 * 40; it += 256) {
        int r = it / 40, c = it - r * 40;
        bf16x8 v = *(const bf16x8*)(pairG + (size_t)(e0 + r) * 320 + c * 8);
        *(bf16x8*)(smem + r * 640 + ((c * 16) ^ ((r & 7) << 4))) = v;
    }
}

// write bn1(relu) of this wave's 128 h1 columns into the 256-col a1 chunk buffer
__device__ __forceinline__ void write_a1_chunk(char* a1buf, const f32x4 (&acc)[4][8], int w, int lane,
                                               const float* __restrict__ b1,
                                               const float* __restrict__ scale1,
                                               const float* __restrict__ shift1) {
    const int cb = w * 128;
    #pragma unroll
    for (int n = 0; n < 8; ++n) {
        int col = cb + n * 16 + (lane & 15);
        int colc = col & 255;
        float bb = b1[col], sc = scale1[col], sh = shift1[col];
        #pragma unroll
        for (int m = 0; m < 4; ++m)
            #pragma unroll
            for (int rr = 0; rr < 4; ++rr) {
                int row = m * 16 + ((lane >> 4) << 2) + rr;
                float a = fmaxf(fmaf(acc[m][n][rr] + bb, sc, sh), 0.f);
                *(bf16*)(a1buf + row * 512 + ((colc * 2) ^ ((row & 7) << 4))) = (bf16)a;
            }
    }
}

__device__ __forceinline__ void gemm2_half(const char* a1buf, const bf16* __restrict__ W2T,
                                           int w, int lane, int kg0, f32x4 (&acc2)[4][4]) {
    #pragma unroll 2
    for (int ks = 0; ks < 8; ++ks) {
        bf16x8 a[4];
        #pragma unroll
        for (int m = 0; m < 4; ++m) a[m] = lds_afrag(a1buf, 256, m * 16, ks * 32, lane);
        #pragma unroll
        for (int n = 0; n < 4; ++n) {
            bf16x8 b = glb_bfrag(W2T, 512, w * 64 + n * 16, kg0 + ks * 32, lane);
            #pragma unroll
            for (int m = 0; m < 4; ++m) acc2[m][n] = MFMA16(a[m], b, acc2[m][n]);
        }
    }
}

// GEMM3..6 tail; expects a2 [64][256] bf16 swizzled at smem+0. Uses smem up to 24704 B.
__device__ __forceinline__ void mlp_tail(char* smem,
                                         const bf16* __restrict__ W3T, const float* __restrict__ b3,
                                         const bf16* __restrict__ W4T, const float* __restrict__ b4,
                                         const bf16* __restrict__ W5T, const float* __restrict__ b5,
                                         const float* __restrict__ W6, const float* __restrict__ b6,
                                         float* __restrict__ out, int E, int e0,
                                         int tid, int lane, int w) {
    // GEMM3: [64][256] @ [256][128]
    f32x4 acc3[4][2];
    #pragma unroll
    for (int m = 0; m < 4; ++m)
        #pragma unroll
        for (int n = 0; n < 2; ++n) acc3[m][n] = (f32x4){0.f, 0.f, 0.f, 0.f};
    for (int ks = 0; ks < 8; ++ks) {
        bf16x8 a[4];
        #pragma unroll
        for (int m = 0; m < 4; ++m) a[m] = lds_afrag(smem, 256, m * 16, ks * 32, lane);
        #pragma unroll
        for (int n = 0; n < 2; ++n) {
            bf16x8 b = glb_bfrag(W3T, 256, w * 32 + n * 16, ks * 32, lane);
            #pragma unroll
            for (int m = 0; m < 4; ++m) acc3[m][n] = MFMA16(a[m], b, acc3[m][n]);
        }
    }
    __syncthreads();
    if (tid < 32) ((float*)(smem + 24576))[tid] = W6[tid];  // a2 upper half is dead now
    #pragma unroll
    for (int n = 0; n < 2; ++n) {
        int col = w * 32 + n * 16 + (lane & 15);
        float bb = b3[col];
        #pragma unroll
        for (int m = 0; m < 4; ++m)
            #pragma unroll
            for (int rr = 0; rr < 4; ++rr) {
                int row = m * 16 + ((lane >> 4) << 2) + rr;
                float a = fmaxf(acc3[m][n][rr] + bb, 0.f);
                *(bf16*)(smem + row * 256 + ((col * 2) ^ ((row & 7) << 4))) = (bf16)a;
            }
    }
    __syncthreads();

    // GEMM4: [64][128] @ [128][64]
    f32x4 acc4[4];
    #pragma unroll
    for (int m = 0; m < 4; ++m) acc4[m] = (f32x4){0.f, 0.f, 0.f, 0.f};
    for (int ks = 0; ks < 4; ++ks) {
        bf16x8 a[4];
        #pragma unroll
        for (int m = 0; m < 4; ++m) a[m] = lds_afrag(smem, 128, m * 16, ks * 32, lane);
        bf16x8 b = glb_bfrag(W4T, 128, w * 16, ks * 32, lane);
        #pragma unroll
        for (int m = 0; m < 4; ++m) acc4[m] = MFMA16(a[m], b, acc4[m]);
    }
    __syncthreads();
    {
        int col = w * 16 + (lane & 15);
        float bb = b4[col];
        #pragma unroll
        for (int m = 0; m < 4; ++m)
            #pragma unroll
            for (int rr = 0; rr < 4; ++rr) {
                int row = m * 16 + ((lane >> 4) << 2) + rr;
                float a = fmaxf(acc4[m][rr] + bb, 0.f);
                *(bf16*)(smem + row * 128 + ((col * 2) ^ ((row & 7) << 4))) = (bf16)a;
            }
    }
    __syncthreads();

    // GEMM5: [64][64] @ [64][32] -> a5 f32 at smem+16384 (waves 0,1)
    if (w < 2) {
        f32x4 acc5[4];
        #pragma unroll
        for (int m = 0; m < 4; ++m) acc5[m] = (f32x4){0.f, 0.f, 0.f, 0.f};
        for (int ks = 0; ks < 2; ++ks) {
            bf16x8 a[4];
            #pragma unroll
            for (int m = 0; m < 4; ++m) a[m] = lds_afrag(smem, 64, m * 16, ks * 32, lane);
            bf16x8 b = glb_bfrag(W5T, 64, w * 16, ks * 32, lane);
            #pragma unroll
            for (int m = 0; m < 4; ++m) acc5[m] = MFMA16(a[m], b, acc5[m]);
        }
        int col = w * 16 + (lane & 15);
        float bb = b5[col];
        float* a5f = (float*)(smem + 16384);
        #pragma unroll
        for (int m = 0; m < 4; ++m)
            #pragma unroll
            for (int rr = 0; rr < 4; ++rr) {
                int row = m * 16 + ((lane >> 4) << 2) + rr;
                a5f[row * 32 + col] = fmaxf(acc5[m][rr] + bb, 0.f);
            }
    }
    __syncthreads();

    if (tid < 64) {
        int ge = e0 + tid;
        if (ge < E) {
            const float* a5f = (const float*)(smem + 16384) + tid * 32;
            const float* w6 = (const float*)(smem + 24576);
            float s = b6[0];
            #pragma unroll
            for (int k = 0; k < 32; ++k) {
                int kk = (k + tid) & 31;
                s = fmaf(a5f[kk], w6[kk], s);
            }
            out[ge] = s;
        }
    }
}

// ---------------- new phase kernels ----------------

// Phase A: gather pair -> LDS + global pairG, GEMM1, stats1.
__global__ __launch_bounds__(256, 4)
void k_mlpA(const float* __restrict__ x, const int* __restrict__ ei, const float* __restrict__ ef,
            const bf16* __restrict__ W1T, const float* __restrict__ b1,
            float* __restrict__ sum1, float* __restrict__ sq1,
            bf16* __restrict__ pairG, int E) {
    __shared__ char smem[40960];
    const int tid = threadIdx.x, lane = tid & 63, w = tid >> 6;
    const int e0 = blockIdx.x * 64;
    const int* src = ei;
    const int* dst = ei + E;

    for (int it = tid; it < 64 * 40; it += 256) {
        int r = it / 40, c = it - r * 40;
        int ge = e0 + r;
        float4 fa = {0, 0, 0, 0}, fb = {0, 0, 0, 0};
        if (ge < E) {
            int base = c * 8;
            const float* p;
            if (base < 128)      p = x + (size_t)src[ge] * 128 + base;
            else if (base < 256) p = x + (size_t)dst[ge] * 128 + (base - 128);
            else                 p = ef + (size_t)ge * 64 + (base - 256);
            fa = *(const float4*)p;
            fb = *(const float4*)(p + 4);
        }
        bf16x8 v = to_bf16x8(fa, fb);
        *(bf16x8*)(smem + r * 640 + ((c * 16) ^ ((r & 7) << 4))) = v;
        *(bf16x8*)(pairG + (size_t)ge * 320 + c * 8) = v;  // pairG padded to grid*64 rows
    }
    __syncthreads();

    f32x4 acc[4][8];
    run_gemm1(smem, W1T, w, lane, acc);

    const int cb = w * 128;
    #pragma unroll
    for (int n = 0; n < 8; ++n) {
        int col = cb + n * 16 + (lane & 15);
        float bb = b1[col];
        float s = 0.f, q = 0.f;
        #pragma unroll
        for (int m = 0; m < 4; ++m)
            #pragma unroll
            for (int rr = 0; rr < 4; ++rr) {
                int row = m * 16 + ((lane >> 4) << 2) + rr;
                if (e0 + row < E) {
                    float h = acc[m][n][rr] + bb;
                    s += h; q += h * h;
                }
            }
        s += __shfl_xor(s, 16); s += __shfl_xor(s, 32);
        q += __shfl_xor(q, 16); q += __shfl_xor(q, 32);
        if (lane < 16) { atomicAdd(&sum1[col], s); atomicAdd(&sq1[col], q); }
    }
}

// Phase B: pairG -> GEMM1 -> bn1 -> GEMM2 (split-K staged a1) -> stats2 [+ h2 f32 store]
template <int STORE_H2>
__global__ __launch_bounds__(256, 4)
void k_mlpB(const bf16* __restrict__ pairG,
            const bf16* __restrict__ W1T, const float* __restrict__ b1,
            const bf16* __restrict__ W2T, const float* __restrict__ b2,
            const float* __restrict__ scale1, const float* __restrict__ shift1,
            float* __restrict__ sum2, float* __restrict__ sq2,
            float* __restrict__ h2G, int E) {
    __shared__ char smem[40960];
    const int tid = threadIdx.x, lane = tid & 63, w = tid >> 6;
    const int e0 = blockIdx.x * 64;

    stage_pair_glb(smem, pairG, e0, tid);
    __syncthreads();

    f32x4 acc[4][8];
    run_gemm1(smem, W1T, w, lane, acc);
    __syncthreads();  // all waves done reading pair tile

    char* a1buf = smem;  // [64][256] bf16 swizzled, reused for both K-chunks
    f32x4 acc2[4][4];
    #pragma unroll
    for (int m = 0; m < 4; ++m)
        #pragma unroll
        for (int n = 0; n < 4; ++n) acc2[m][n] = (f32x4){0.f, 0.f, 0.f, 0.f};

    if (w < 2) write_a1_chunk(a1buf, acc, w, lane, b1, scale1, shift1);  // cols 0..255
    __syncthreads();
    gemm2_half(a1buf, W2T, w, lane, 0, acc2);
    __syncthreads();
    if (w >= 2) write_a1_chunk(a1buf, acc, w, lane, b1, scale1, shift1); // cols 256..511
    __syncthreads();
    gemm2_half(a1buf, W2T, w, lane, 256, acc2);

    const int cb2 = w * 64;
    #pragma unroll
    for (int n = 0; n < 4; ++n) {
        int col = cb2 + n * 16 + (lane & 15);
        float bb = b2[col];
        float s = 0.f, q = 0.f;
        #pragma unroll
        for (int m = 0; m < 4; ++m)
            #pragma unroll
            for (int rr = 0; rr < 4; ++rr) {
                int row = m * 16 + ((lane >> 4) << 2) + rr;
                float h = acc2[m][n][rr] + bb;
                if (STORE_H2) h2G[(size_t)(e0 + row) * 256 + col] = h;
                if (e0 + row < E) { s += h; q += h * h; }
            }
        s += __shfl_xor(s, 16); s += __shfl_xor(s, 32);
        q += __shfl_xor(q, 16); q += __shfl_xor(q, 32);
        if (lane < 16) { atomicAdd(&sum2[col], s); atomicAdd(&sq2[col], q); }
    }
}

// Phase C (FULL): h2G f32 -> bn2 during staging -> GEMM3..6 -> out
__global__ __launch_bounds__(256, 4)
void k_mlpC_h2(const float* __restrict__ h2G,
               const bf16* __restrict__ W3T, const float* __restrict__ b3,
               const bf16* __restrict__ W4T, const float* __restrict__ b4,
               const bf16* __restrict__ W5T, const float* __restrict__ b5,
               const float* __restrict__ W6, const float* __restrict__ b6,
               const float* __restrict__ scale2, const float* __restrict__ shift2,
               float* __restrict__ out, int E) {
    __shared__ char smem[32768];
    const int tid = threadIdx.x, lane = tid & 63, w = tid >> 6;
    const int e0 = blockIdx.x * 64;

    for (int it = tid; it < 64 * 32; it += 256) {
        int r = it >> 5, c = it & 31;
        const float* p = h2G + (size_t)(e0 + r) * 256 + c * 8;
        float4 fa = *(const float4*)p;
        float4 fb = *(const float4*)(p + 4);
        float4 s0 = *(const float4*)(scale2 + c * 8);
        float4 s1 = *(const float4*)(scale2 + c * 8 + 4);
        float4 h0 = *(const float4*)(shift2 + c * 8);
        float4 h1 = *(const float4*)(shift2 + c * 8 + 4);
        float4 ra, rb;
        ra.x = fmaxf(fmaf(fa.x, s0.x, h0.x), 0.f);
        ra.y = fmaxf(fmaf(fa.y, s0.y, h0.y), 0.f);
        ra.z = fmaxf(fmaf(fa.z, s0.z, h0.z), 0.f);
        ra.w = fmaxf(fmaf(fa.w, s0.w, h0.w), 0.f);
        rb.x = fmaxf(fmaf(fb.x, s1.x, h1.x), 0.f);
        rb.y = fmaxf(fmaf(fb.y, s1.y, h1.y), 0.f);
        rb.z = fmaxf(fmaf(fb.z, s1.z, h1.z), 0.f);
        rb.w = fmaxf(fmaf(fb.w, s1.w, h1.w), 0.f);
        bf16x8 v = to_bf16x8(ra, rb);
        *(bf16x8*)(smem + r * 512 + ((c * 16) ^ ((r & 7) << 4))) = v;
    }
    __syncthreads();

    mlp_tail(smem, W3T, b3, W4T, b4, W5T, b5, W6, b6, out, E, e0, tid, lane, w);
}

// Phase C (PAIR): recompute GEMM1/bn1/GEMM2 from pairG, then bn2 -> GEMM3..6 -> out
__global__ __launch_bounds__(256, 4)
void k_mlpC_pair(const bf16* __restrict__ pairG,
                 const bf16* __restrict__ W1T, const float* __restrict__ b1,
                 const bf16* __restrict__ W2T, const float* __restrict__ b2,
                 const bf16* __restrict__ W3T, const float* __restrict__ b3,
                 const bf16* __restrict__ W4T, const float* __restrict__ b4,
                 const bf16* __restrict__ W5T, const float* __restrict__ b5,
                 const float* __restrict__ W6, const float* __restrict__ b6,
                 const float* __restrict__ scale1, const float* __restrict__ shift1,
                 const float* __restrict__ scale2, const float* __restrict__ shift2,
                 float* __restrict__ out, int E) {
    __shared__ char smem[40960];
    const int tid = threadIdx.x, lane = tid & 63, w = tid >> 6;
    const int e0 = blockIdx.x * 64;

    stage_pair_glb(smem, pairG, e0, tid);
    __syncthreads();

    f32x4 acc[4][8];
    run_gemm1(smem, W1T, w, lane, acc);
    __syncthreads();

    char* a1buf = smem;
    f32x4 acc2[4][4];
    #pragma unroll
    for (int m = 0; m < 4; ++m)
        #pragma unroll
        for (int n = 0; n < 4; ++n) acc2[m][n] = (f32x4){0.f, 0.f, 0.f, 0.f};

    if (w < 2) write_a1_chunk(a1buf, acc, w, lane, b1, scale1, shift1);
    __syncthreads();
    gemm2_half(a1buf, W2T, w, lane, 0, acc2);
    __syncthreads();
    if (w >= 2) write_a1_chunk(a1buf, acc, w, lane, b1, scale1, shift1);
    __syncthreads();
    gemm2_half(a1buf, W2T, w, lane, 256, acc2);
    __syncthreads();  // done reading a1buf; reuse as a2

    const int cb2 = w * 64;
    #pragma unroll
    for (int n = 0; n < 4; ++n) {
        int col = cb2 + n * 16 + (lane & 15);
        float bb = b2[col], sc = scale2[col], sh = shift2[col];
        #pragma unroll
        for (int m = 0; m < 4; ++m)
            #pragma unroll
            for (int rr = 0; rr < 4; ++rr) {
                int row = m * 16 + ((lane >> 4) << 2) + rr;
                float a = fmaxf(fmaf(acc2[m][n][rr] + bb, sc, sh), 0.f);
                *(bf16*)(smem + row * 512 + ((col * 2) ^ ((row & 7) << 4))) = (bf16)a;
            }
    }
    __syncthreads();

    mlp_tail(smem, W3T, b3, W4T, b4, W5T, b5, W6, b6, out, E, e0, tid, lane, w);
}

// ---------------- OLD fallback: fused edge MLP (3 gather passes) ----------------
template <int PASS>
__global__ __launch_bounds__(256, 2)
void k_mlp(const float* __restrict__ x, const int* __restrict__ ei, const float* __restrict__ ef,
           const bf16* __restrict__ W1T, const float* __restrict__ b1,
           const bf16* __restrict__ W2T, const float* __restrict__ b2,
           const bf16* __restrict__ W3T, const float* __restrict__ b3,
           const bf16* __restrict__ W4T, const float* __restrict__ b4,
           const bf16* __restrict__ W5T, const float* __restrict__ b5,
           const float* __restrict__ W6, const float* __restrict__ b6,
           const float* __restrict__ scale1, const float* __restrict__ shift1,
           const float* __restrict__ scale2, const float* __restrict__ shift2,
           float* __restrict__ sum1, float* __restrict__ sq1,
           float* __restrict__ sum2, float* __restrict__ sq2,
           float* __restrict__ out, int E) {
    __shared__ char smem[65536];
    const int tid = threadIdx.x, lane = tid & 63, w = tid >> 6;
    const int e0 = blockIdx.x * 64;
    const int* src = ei;
    const int* dst = ei + E;

    for (int it = tid; it < 64 * 40; it += 256) {
        int r = it / 40, c = it - r * 40;
        int ge = e0 + r;
        float4 fa = {0, 0, 0, 0}, fb = {0, 0, 0, 0};
        if (ge < E) {
            int base = c * 8;
            const float* p;
            if (base < 128)      p = x + (size_t)src[ge] * 128 + base;
            else if (base < 256) p = x + (size_t)dst[ge] * 128 + (base - 128);
            else                 p = ef + (size_t)ge * 64 + (base - 256);
            fa = *(const float4*)p;
            fb = *(const float4*)(p + 4);
        }
        bf16x8 v = to_bf16x8(fa, fb);
        *(bf16x8*)(smem + r * 640 + ((c * 16) ^ ((r & 7) << 4))) = v;
    }
    __syncthreads();

    f32x4 acc[4][8];
    run_gemm1(smem, W1T, w, lane, acc);
    const int cb = w * 128;

    if (PASS == 0) {
        #pragma unroll
        for (int n = 0; n < 8; ++n) {
            int col = cb + n * 16 + (lane & 15);
            float bb = b1[col];
            float s = 0.f, q = 0.f;
            #pragma unroll
            for (int m = 0; m < 4; ++m)
                #pragma unroll
                for (int rr = 0; rr < 4; ++rr) {
                    int row = m * 16 + ((lane >> 4) << 2) + rr;
                    if (e0 + row < E) {
                        float h = acc[m][n][rr] + bb;
                        s += h; q += h * h;
                    }
                }
            s += __shfl_xor(s, 16); s += __shfl_xor(s, 32);
            q += __shfl_xor(q, 16); q += __shfl_xor(q, 32);
            if (lane < 16) { atomicAdd(&sum1[col], s); atomicAdd(&sq1[col], q); }
        }
        return;
    }

    __syncthreads();
    #pragma unroll
    for (int n = 0; n < 8; ++n) {
        int col = cb + n * 16 + (lane & 15);
        float bb = b1[col], sc = scale1[col], sh = shift1[col];
        #pragma unroll
        for (int m = 0; m < 4; ++m)
            #pragma unroll
            for (int rr = 0; rr < 4; ++rr) {
                int row = m * 16 + ((lane >> 4) << 2) + rr;
                float a = fmaxf(fmaf(acc[m][n][rr] + bb, sc, sh), 0.f);
                *(bf16*)(smem + row * 1024 + ((col * 2) ^ ((row & 7) << 4))) = (bf16)a;
            }
    }
    __syncthreads();

    f32x4 acc2[4][4];
    #pragma unroll
    for (int m = 0; m < 4; ++m)
        #pragma unroll
        for (int n = 0; n < 4; ++n) acc2[m][n] = (f32x4){0.f, 0.f, 0.f, 0.f};
    #pragma unroll 2
    for (int ks = 0; ks < 16; ++ks) {
        bf16x8 a[4];
        #pragma unroll
        for (int m = 0; m < 4; ++m) a[m] = lds_afrag(smem, 512, m * 16, ks * 32, lane);
        #pragma unroll
        for (int n = 0; n < 4; ++n) {
            bf16x8 b = glb_bfrag(W2T, 512, w * 64 + n * 16, ks * 32, lane);
            #pragma unroll
            for (int m = 0; m < 4; ++m) acc2[m][n] = MFMA16(a[m], b, acc2[m][n]);
        }
    }
    const int cb2 = w * 64;

    if (PASS == 1) {
        #pragma unroll
        for (int n = 0; n < 4; ++n) {
            int col = cb2 + n * 16 + (lane & 15);
            float bb = b2[col];
            float s = 0.f, q = 0.f;
            #pragma unroll
            for (int m = 0; m < 4; ++m)
                #pragma unroll
                for (int rr = 0; rr < 4; ++rr) {
                    int row = m * 16 + ((lane >> 4) << 2) + rr;
                    if (e0 + row < E) {
                        float h = acc2[m][n][rr] + bb;
                        s += h; q += h * h;
                    }
                }
            s += __shfl_xor(s, 16); s += __shfl_xor(s, 32);
            q += __shfl_xor(q, 16); q += __shfl_xor(q, 32);
            if (lane < 16) { atomicAdd(&sum2[col], s); atomicAdd(&sq2[col], q); }
        }
        return;
    }

    __syncthreads();
    if (tid < 32) *(float*)(smem + 49152 + tid * 4) = W6[tid];
    #pragma unroll
    for (int n = 0; n < 4; ++n) {
        int col = cb2 + n * 16 + (lane & 15);
        float bb = b2[col], sc = scale2[col], sh = shift2[col];
        #pragma unroll
        for (int m = 0; m < 4; ++m)
            #pragma unroll
            for (int rr = 0; rr < 4; ++rr) {
                int row = m * 16 + ((lane >> 4) << 2) + rr;
                float a = fmaxf(fmaf(acc2[m][n][rr] + bb, sc, sh), 0.f);
                *(bf16*)(smem + row * 512 + ((col * 2) ^ ((row & 7) << 4))) = (bf16)a;
            }
    }
    __syncthreads();

    f32x4 acc3[4][2];
    #pragma unroll
    for (int m = 0; m < 4; ++m)
        #pragma unroll
        for (int n = 0; n < 2; ++n) acc3[m][n] = (f32x4){0.f, 0.f, 0.f, 0.f};
    for (int ks = 0; ks < 8; ++ks) {
        bf16x8 a[4];
        #pragma unroll
        for (int m = 0; m < 4; ++m) a[m] = lds_afrag(smem, 256, m * 16, ks * 32, lane);
        #pragma unroll
        for (int n = 0; n < 2; ++n) {
            bf16x8 b = glb_bfrag(W3T, 256, w * 32 + n * 16, ks * 32, lane);
            #pragma unroll
            for (int m = 0; m < 4; ++m) acc3[m][n] = MFMA16(a[m], b, acc3[m][n]);
        }
    }
    __syncthreads();
    #pragma unroll
    for (int n = 0; n < 2; ++n) {
        int col = w * 32 + n * 16 + (lane & 15);
        float bb = b3[col];
        #pragma unroll
        for (int m = 0; m < 4; ++m)
            #pragma unroll
            for (int rr = 0; rr < 4; ++rr) {
                int row = m * 16 + ((lane >> 4) << 2) + rr;
                float a = fmaxf(acc3[m][n][rr] + bb, 0.f);
                *(bf16*)(smem + row * 256 + ((col * 2) ^ ((row & 7) << 4))) = (bf16)a;
            }
    }
    __syncthreads();

    f32x4 acc4[4];
    #pragma unroll
    for (int m = 0; m < 4; ++m) acc4[m] = (f32x4){0.f, 0.f, 0.f, 0.f};
    for (int ks = 0; ks < 4; ++ks) {
        bf16x8 a[4];
        #pragma unroll
        for (int m = 0; m < 4; ++m) a[m] = lds_afrag(smem, 128, m * 16, ks * 32, lane);
        bf16x8 b = glb_bfrag(W4T, 128, w * 16, ks * 32, lane);
        #pragma unroll
        for (int m = 0; m < 4; ++m) acc4[m] = MFMA16(a[m], b, acc4[m]);
    }
    __syncthreads();
    {
        int col = w * 16 + (lane & 15);
        float bb = b4[col];
        #pragma unroll
        for (int m = 0; m < 4; ++m)
            #pragma unroll
            for (int rr = 0; rr < 4; ++rr) {
                int row = m * 16 + ((lane >> 4) << 2) + rr;
                float a = fmaxf(acc4[m][rr] + bb, 0.f);
                *(bf16*)(smem + row * 128 + ((col * 2) ^ ((row & 7) << 4))) = (bf16)a;
            }
    }
    __syncthreads();

    if (w < 2) {
        f32x4 acc5[4];
        #pragma unroll
        for (int m = 0; m < 4; ++m) acc5[m] = (f32x4){0.f, 0.f, 0.f, 0.f};
        for (int ks = 0; ks < 2; ++ks) {
            bf16x8 a[4];
            #pragma unroll
            for (int m = 0; m < 4; ++m) a[m] = lds_afrag(smem, 64, m * 16, ks * 32, lane);
            bf16x8 b = glb_bfrag(W5T, 64, w * 16, ks * 32, lane);
            #pragma unroll
            for (int m = 0; m < 4; ++m) acc5[m] = MFMA16(a[m], b, acc5[m]);
        }
        int col = w * 16 + (lane & 15);
        float bb = b5[col];
        float* a5f = (float*)(smem + 16384);
        #pragma unroll
        for (int m = 0; m < 4; ++m)
            #pragma unroll
            for (int rr = 0; rr < 4; ++rr) {
                int row = m * 16 + ((lane >> 4) << 2) + rr;
                a5f[row * 32 + col] = fmaxf(acc5[m][rr] + bb, 0.f);
            }
    }
    __syncthreads();

    if (tid < 64) {
        int ge = e0 + tid;
        if (ge < E) {
            const float* a5f = (const float*)(smem + 16384) + tid * 32;
            const float* w6 = (const float*)(smem + 49152);
            float s = b6[0];
            #pragma unroll
            for (int k = 0; k < 32; ++k) {
                int kk = (k + tid) & 31;
                s = fmaf(a5f[kk], w6[kk], s);
            }
            out[ge] = s;
        }
    }
}

// ---------------- launch ----------------

extern "C" void kernel_launch(void* const* d_in, const int* in_sizes, int n_in,
                              void* d_out, int out_size, void* d_ws, size_t ws_size,
                              hipStream_t stream) {
    const float* x      = (const float*)d_in[0];
    const int*   ei     = (const int*)d_in[1];
    const float* ef     = (const float*)d_in[2];
    const float* W_nb   = (const float*)d_in[4];
    const float* b_nb   = (const float*)d_in[5];
    const float* W_self = (const float*)d_in[6];
    const float* b_self = (const float*)d_in[7];
    const float* W1 = (const float*)d_in[8];  const float* b1 = (const float*)d_in[9];
    const float* W2 = (const float*)d_in[10]; const float* b2 = (const float*)d_in[11];
    const float* W3 = (const float*)d_in[12]; const float* b3 = (const float*)d_in[13];
    const float* W4 = (const float*)d_in[14]; const float* b4 = (const float*)d_in[15];
    const float* W5 = (const float*)d_in[16]; const float* b5 = (const float*)d_in[17];
    const float* W6 = (const float*)d_in[18]; const float* b6 = (const float*)d_in[19];
    const float* g1 = (const float*)d_in[20]; const float* beta1 = (const float*)d_in[21];
    const float* g2 = (const float*)d_in[22]; const float* beta2 = (const float*)d_in[23];

    const int N = in_sizes[0] / 128;
    const int E = in_sizes[1] / 2;
    const int mlpGrid = (E + 63) / 64;
    const size_t Epad = (size_t)mlpGrid * 64;

    char* ws = (char*)d_ws;
    size_t off = 0;
    auto alloc = [&](size_t bytes) {
        size_t o = off;
        off = (off + bytes + 255) & ~(size_t)255;
        return o;
    };
    size_t oDeg = alloc((size_t)N * 4);
    size_t oCur = alloc((size_t)N * 4);
    size_t oSum1 = alloc(512 * 4), oSq1 = alloc(512 * 4);
    size_t oSum2 = alloc(256 * 4), oSq2 = alloc(256 * 4);
    size_t zeroEnd = off;
    size_t oOff = alloc((size_t)(N + 1) * 4);
    size_t oInv = alloc((size_t)N * 4);
    size_t oEid = alloc((size_t)E * 4);
    size_t oSm  = alloc((size_t)N * 192 * 4);
    size_t oXb1 = alloc((size_t)N * 128 * 4);
    size_t oXb2 = alloc((size_t)N * 128 * 4);
    size_t oScale1 = alloc(512 * 4), oShift1 = alloc(512 * 4);
    size_t oScale2 = alloc(256 * 4), oShift2 = alloc(256 * 4);
    size_t oWcat = alloc(128 * 320 * 2);
    size_t oW1T = alloc((size_t)512 * 320 * 2);
    size_t oW2T = alloc((size_t)256 * 512 * 2);
    size_t oW3T = alloc((size_t)128 * 256 * 2);
    size_t oW4T = alloc((size_t)64 * 128 * 2);
    size_t oW5T = alloc((size_t)32 * 64 * 2);
    size_t baseEnd = off;
    size_t oPair = alloc(Epad * 320 * 2);   // bf16 pair tile
    size_t pairEnd = off;
    size_t oH2 = alloc(Epad * 256 * 4);     // f32 h2
    size_t fullEnd = off;

    int mode = (ws_size >= fullEnd) ? 2 : (ws_size >= pairEnd) ? 1 : (ws_size >= baseEnd) ? 0 : -1;
    if (mode < 0) return;

    float* deg = (float*)(ws + oDeg);
    unsigned* cursor = (unsigned*)(ws + oCur);
    float* sum1 = (float*)(ws + oSum1); float* sq1 = (float*)(ws + oSq1);
    float* sum2 = (float*)(ws + oSum2); float* sq2 = (float*)(ws + oSq2);
    unsigned* offsets = (unsigned*)(ws + oOff);
    float* invdeg = (float*)(ws + oInv);
    unsigned* eid = (unsigned*)(ws + oEid);
    float* sm  = (float*)(ws + oSm);
    float* xb1 = (float*)(ws + oXb1);
    float* xb2 = (float*)(ws + oXb2);
    float* scale1 = (float*)(ws + oScale1); float* shift1 = (float*)(ws + oShift1);
    float* scale2 = (float*)(ws + oScale2); float* shift2 = (float*)(ws + oShift2);
    bf16* WcatT = (bf16*)(ws + oWcat);
    bf16* W1T = (bf16*)(ws + oW1T);
    bf16* W2T = (bf16*)(ws + oW2T);
    bf16* W3T = (bf16*)(ws + oW3T);
    bf16* W4T = (bf16*)(ws + oW4T);
    bf16* W5T = (bf16*)(ws + oW5T);
    bf16* pairG = (bf16*)(ws + oPair);
    float* h2G = (float*)(ws + oH2);

    hipMemsetAsync(ws, 0, zeroEnd, stream);

    k_transpose<<<(128 * 128 + 255) / 256, 256, 0, stream>>>(W_self, WcatT, 128, 128, 320, 0);
    k_transpose<<<(192 * 128 + 255) / 256, 256, 0, stream>>>(W_nb, WcatT, 192, 128, 320, 128);
    k_transpose<<<(320 * 512 + 255) / 256, 256, 0, stream>>>(W1, W1T, 320, 512, 320, 0);
    k_transpose<<<(512 * 256 + 255) / 256, 256, 0, stream>>>(W2, W2T, 512, 256, 512, 0);
    k_transpose<<<(256 * 128 + 255) / 256, 256, 0, stream>>>(W3, W3T, 256, 128, 256, 0);
    k_transpose<<<(128 * 64 + 255) / 256, 256, 0, stream>>>(W4, W4T, 128, 64, 128, 0);
    k_transpose<<<(64 * 32 + 255) / 256, 256, 0, stream>>>(W5, W5T, 64, 32, 64, 0);

    const int* dst = ei + E;
    k_deg<<<(E + 255) / 256, 256, 0, stream>>>(dst, deg, E);
    k_scan<<<1, 1024, 0, stream>>>(deg, offsets, invdeg, N);
    k_scatter<<<(E + 255) / 256, 256, 0, stream>>>(dst, offsets, cursor, eid, E);

    k_agg<<<(N + 15) / 16, 256, 0, stream>>>(x, ef, ei, offsets, invdeg, eid, sm, N);
    k_nodegemm<<<(N + 63) / 64, 256, 0, stream>>>(x, sm, WcatT, b_self, b_nb, offsets, xb1, N);
    k_agg<<<(N + 15) / 16, 256, 0, stream>>>(xb1, ef, ei, offsets, invdeg, eid, sm, N);
    k_nodegemm<<<(N + 63) / 64, 256, 0, stream>>>(xb1, sm, WcatT, b_self, b_nb, offsets, xb2, N);

    const float invE = 1.0f / (float)E;
    if (mode >= 1) {
        k_mlpA<<<mlpGrid, 256, 0, stream>>>(xb2, ei, ef, W1T, b1, sum1, sq1, pairG, E);
        k_finalize<<<2, 256, 0, stream>>>(sum1, sq1, g1, beta1, scale1, shift1, 512, invE);
        if (mode == 2) {
            k_mlpB<1><<<mlpGrid, 256, 0, stream>>>(pairG, W1T, b1, W2T, b2, scale1, shift1,
                                                   sum2, sq2, h2G, E);
            k_finalize<<<1, 256, 0, stream>>>(sum2, sq2, g2, beta2, scale2, shift2, 256, invE);
            k_mlpC_h2<<<mlpGrid, 256, 0, stream>>>(h2G, W3T, b3, W4T, b4, W5T, b5, W6, b6,
                                                   scale2, shift2, (float*)d_out, E);
        } else {
            k_mlpB<0><<<mlpGrid, 256, 0, stream>>>(pairG, W1T, b1, W2T, b2, scale1, shift1,
                                                   sum2, sq2, h2G, E);
            k_finalize<<<1, 256, 0, stream>>>(sum2, sq2, g2, beta2, scale2, shift2, 256, invE);
            k_mlpC_pair<<<mlpGrid, 256, 0, stream>>>(pairG, W1T, b1, W2T, b2, W3T, b3, W4T, b4,
                                                     W5T, b5, W6, b6, scale1, shift1,
                                                     scale2, shift2, (float*)d_out, E);
        }
    } else {
        k_mlp<0><<<mlpGrid, 256, 0, stream>>>(xb2, ei, ef, W1T, b1, W2T, b2, W3T, b3, W4T, b4,
                                              W5T, b5, W6, b6, scale1, shift1, scale2, shift2,
                                              sum1, sq1, sum2, sq2, (float*)d_out, E);
        k_finalize<<<2, 256, 0, stream>>>(sum1, sq1, g1, beta1, scale1, shift1, 512, invE);
        k_mlp<1><<<mlpGrid, 256, 0, stream>>>(xb2, ei, ef, W1T, b1, W2T, b2, W3T, b3, W4T, b4,
                                              W5T, b5, W6, b6, scale1, shift1, scale2, shift2,
                                              sum1, sq1, sum2, sq2, (float*)d_out, E);
        k_finalize<<<1, 256, 0, stream>>>(sum2, sq2, g2, beta2, scale2, shift2, 256, invE);
        k_mlp<2><<<mlpGrid, 256, 0, stream>>>(xb2, ei, ef, W1T, b1, W2T, b2, W3T, b3, W4T, b4,
                                              W5T, b5, W6, b6, scale1, shift1, scale2, shift2,
                                              sum1, sq1, sum2, sq2, (float*)d_out, E);
    }
}

// Round 4
// 3222.056 us; speedup vs baseline: 1.8752x; 1.8752x over previous
//
#include <hip/hip_runtime.h>

using bf16 = __bf16;
typedef bf16 bf16x8 __attribute__((ext_vector_type(8)));
typedef float f32x4 __attribute__((ext_vector_type(4)));

#define MFMA16(a, b, c) __builtin_amdgcn_mfma_f32_16x16x32_bf16(a, b, c, 0, 0, 0)

// ---------------- helpers ----------------

__device__ __forceinline__ bf16x8 to_bf16x8(float4 a, float4 b) {
    bf16x8 v;
    v[0] = (bf16)a.x; v[1] = (bf16)a.y; v[2] = (bf16)a.z; v[3] = (bf16)a.w;
    v[4] = (bf16)b.x; v[5] = (bf16)b.y; v[6] = (bf16)b.z; v[7] = (bf16)b.w;
    return v;
}

__device__ __forceinline__ bf16x8 zero_bf16x8() {
    bf16 z = (bf16)0.f;
    bf16x8 v = {z, z, z, z, z, z, z, z};
    return v;
}

// A-fragment from a swizzled row-major LDS tile [rows][ldK] bf16.
// Swizzle: byte_off_in_row ^= ((row&7)<<4). Requires ldK*2 % 128 == 0.
__device__ __forceinline__ bf16x8 lds_afrag(const char* smem, int ldK, int mbase, int kbase, int lane) {
    int r = mbase + (lane & 15);
    int off = (kbase + ((lane >> 4) << 3)) << 1;
    off ^= (r & 7) << 4;
    return *(const bf16x8*)(smem + r * (ldK << 1) + off);
}

// B-fragment from global WT[N][K] bf16 (i.e., W transposed): 8 contiguous k at row n.
__device__ __forceinline__ bf16x8 glb_bfrag(const bf16* __restrict__ WT, int K, int nbase, int kbase, int lane) {
    int n = nbase + (lane & 15);
    int k = kbase + ((lane >> 4) << 3);
    return *(const bf16x8*)(WT + (size_t)n * K + k);
}

// ---------------- small kernels ----------------

__global__ void k_transpose(const float* __restrict__ W, bf16* __restrict__ WT,
                            int K, int N, int ldT, int k0) {
    int idx = blockIdx.x * 256 + threadIdx.x;
    if (idx < K * N) {
        int k = idx / N, n = idx - k * N;
        WT[(size_t)n * ldT + k0 + k] = (bf16)W[idx];
    }
}

__global__ void k_deg(const int* __restrict__ dst, float* __restrict__ deg, int E) {
    int e = blockIdx.x * 256 + threadIdx.x;
    if (e < E) atomicAdd(&deg[dst[e]], 1.0f);
}

__global__ void k_scan(const float* __restrict__ deg, unsigned* __restrict__ offsets,
                       float* __restrict__ invdeg, int N) {
    __shared__ unsigned wsum[16];
    __shared__ unsigned carry_s, tot_s;
    const int tid = threadIdx.x, lane = tid & 63, wid = tid >> 6;
    if (tid == 0) carry_s = 0;
    __syncthreads();
    for (int base = 0; base < N; base += 1024) {
        int i = base + tid;
        unsigned v = (i < N) ? (unsigned)deg[i] : 0u;
        unsigned inc = v;
        #pragma unroll
        for (int d = 1; d < 64; d <<= 1) {
            unsigned t = (unsigned)__shfl_up((int)inc, d, 64);
            if (lane >= d) inc += t;
        }
        if (lane == 63) wsum[wid] = inc;
        __syncthreads();
        if (wid == 0) {
            unsigned wv = (lane < 16) ? wsum[lane] : 0u;
            unsigned winc = wv;
            #pragma unroll
            for (int d = 1; d < 16; d <<= 1) {
                unsigned t = (unsigned)__shfl_up((int)winc, d, 16);
                if ((lane & 15) >= d) winc += t;
            }
            if (lane < 16) wsum[lane] = winc - wv;
            if (lane == 15) tot_s = winc;
        }
        __syncthreads();
        if (i < N) {
            offsets[i] = carry_s + wsum[wid] + (inc - v);
            invdeg[i] = 1.0f / fmaxf(deg[i], 1.0f);
        }
        __syncthreads();
        if (tid == 0) carry_s += tot_s;
        __syncthreads();
    }
    if (tid == 0) offsets[N] = carry_s;
}

__global__ void k_scatter(const int* __restrict__ dst, const unsigned* __restrict__ offsets,
                          unsigned* __restrict__ cursor, unsigned* __restrict__ eid, int E) {
    int e = blockIdx.x * 256 + threadIdx.x;
    if (e < E) {
        int d = dst[e];
        unsigned p = atomicAdd(&cursor[d], 1u);
        eid[offsets[d] + p] = (unsigned)e;
    }
}

__global__ __launch_bounds__(256)
void k_agg(const float* __restrict__ xin, const float* __restrict__ ef, const int* __restrict__ src,
           const unsigned* __restrict__ offsets, const float* __restrict__ invdeg,
           const unsigned* __restrict__ eid, float* __restrict__ sm, int N) {
    const int lane = threadIdx.x & 63, w = threadIdx.x >> 6;
    int nb = blockIdx.x * 16 + w * 4;
    for (int j = 0; j < 4; ++j) {
        int n = nb + j;
        if (n >= N) return;
        unsigned o0 = offsets[n], o1 = offsets[n + 1];
        float s0 = 0.f, s1 = 0.f, s2 = 0.f;
        for (unsigned t = o0; t < o1; ++t) {
            int e = (int)eid[t];
            int v = src[e];
            s0 += xin[(size_t)v * 128 + lane];
            s1 += xin[(size_t)v * 128 + 64 + lane];
            s2 += ef[(size_t)e * 64 + lane];
        }
        float g = invdeg[n];
        sm[(size_t)n * 192 + lane] = s0 * g;
        sm[(size_t)n * 192 + 64 + lane] = s1 * g;
        sm[(size_t)n * 192 + 128 + lane] = s2 * g;
    }
}

// x_out = relu(concat(x, sm) @ Wcat + b_self + (deg>0 ? b_nb : 0))
// BF16OUT=1: write bf16 to xoutB; else f32 to xout.
template <int BF16OUT>
__global__ __launch_bounds__(256)
void k_nodegemm(const float* __restrict__ xin, const float* __restrict__ sm,
                const bf16* __restrict__ WcatT,
                const float* __restrict__ b_self, const float* __restrict__ b_nb,
                const unsigned* __restrict__ offsets,
                float* __restrict__ xout, bf16* __restrict__ xoutB, int N) {
    __shared__ char smem[64 * 320 * 2];
    const int tid = threadIdx.x, lane = tid & 63, w = tid >> 6;
    const int n0 = blockIdx.x * 64;
    for (int it = tid; it < 64 * 40; it += 256) {
        int r = it / 40, c = it - r * 40;
        int node = n0 + r;
        float4 fa = {0, 0, 0, 0}, fb = {0, 0, 0, 0};
        if (node < N) {
            int base = c * 8;
            const float* p = (base < 128) ? xin + (size_t)node * 128 + base
                                          : sm + (size_t)node * 192 + (base - 128);
            fa = *(const float4*)p;
            fb = *(const float4*)(p + 4);
        }
        bf16x8 v = to_bf16x8(fa, fb);
        *(bf16x8*)(smem + r * 640 + ((c * 16) ^ ((r & 7) << 4))) = v;
    }
    __syncthreads();

    f32x4 acc[4][2];
    #pragma unroll
    for (int m = 0; m < 4; ++m)
        #pragma unroll
        for (int n = 0; n < 2; ++n) acc[m][n] = (f32x4){0.f, 0.f, 0.f, 0.f};

    for (int ks = 0; ks < 10; ++ks) {
        bf16x8 a[4];
        #pragma unroll
        for (int m = 0; m < 4; ++m) a[m] = lds_afrag(smem, 320, m * 16, ks * 32, lane);
        #pragma unroll
        for (int n = 0; n < 2; ++n) {
            bf16x8 b = glb_bfrag(WcatT, 320, w * 32 + n * 16, ks * 32, lane);
            #pragma unroll
            for (int m = 0; m < 4; ++m) acc[m][n] = MFMA16(a[m], b, acc[m][n]);
        }
    }

    #pragma unroll
    for (int n = 0; n < 2; ++n) {
        int col = w * 32 + n * 16 + (lane & 15);
        float bs = b_self[col], bn = b_nb[col];
        #pragma unroll
        for (int m = 0; m < 4; ++m)
            #pragma unroll
            for (int rr = 0; rr < 4; ++rr) {
                int row = m * 16 + ((lane >> 4) << 2) + rr;
                int node = n0 + row;
                if (node < N) {
                    bool hd = offsets[node + 1] > offsets[node];
                    float val = fmaxf(acc[m][n][rr] + bs + (hd ? bn : 0.f), 0.f);
                    if (BF16OUT) xoutB[(size_t)node * 128 + col] = (bf16)val;
                    else         xout[(size_t)node * 128 + col] = val;
                }
            }
    }
}

__global__ void k_finalize(const float* __restrict__ sum, const float* __restrict__ sq,
                           const float* __restrict__ g, const float* __restrict__ beta,
                           float* __restrict__ scale, float* __restrict__ shift,
                           int n, float invE) {
    int i = blockIdx.x * 256 + threadIdx.x;
    if (i < n) {
        float m = sum[i] * invE;
        float v = sq[i] * invE - m * m;
        float sc = g[i] * rsqrtf(v + 1e-5f);
        scale[i] = sc;
        shift[i] = beta[i] - m * sc;
    }
}

// ---------------- shared MLP building blocks ----------------

// GEMM1 over a 32-col chunk: acc[4][2] (keeps register pressure low).
__device__ __forceinline__ void gemm1_chunk(const char* P, const bf16* __restrict__ W1T,
                                            int cbase, int lane, f32x4 (&acc)[4][2]) {
    #pragma unroll
    for (int m = 0; m < 4; ++m)
        #pragma unroll
        for (int n = 0; n < 2; ++n) acc[m][n] = (f32x4){0.f, 0.f, 0.f, 0.f};
    for (int ks = 0; ks < 10; ++ks) {
        bf16x8 a[4];
        #pragma unroll
        for (int m = 0; m < 4; ++m) a[m] = lds_afrag(P, 320, m * 16, ks * 32, lane);
        #pragma unroll
        for (int n = 0; n < 2; ++n) {
            bf16x8 b = glb_bfrag(W1T, 320, cbase + n * 16, ks * 32, lane);
            #pragma unroll
            for (int m = 0; m < 4; ++m) acc[m][n] = MFMA16(a[m], b, acc[m][n]);
        }
    }
}

// full-width GEMM1 (acc[4][8]) for the T0 fallback kernel only ((256,2): no spill)
__device__ __forceinline__ void run_gemm1(const char* smem, const bf16* __restrict__ W1T,
                                          int w, int lane, f32x4 (&acc)[4][8]) {
    #pragma unroll
    for (int m = 0; m < 4; ++m)
        #pragma unroll
        for (int n = 0; n < 8; ++n) acc[m][n] = (f32x4){0.f, 0.f, 0.f, 0.f};
    #pragma unroll 2
    for (int ks = 0; ks < 10; ++ks) {
        bf16x8 a[4];
        #pragma unroll
        for (int m = 0; m < 4; ++m) a[m] = lds_afrag(smem, 320, m * 16, ks * 32, lane);
        #pragma unroll
        for (int n = 0; n < 8; ++n) {
            bf16x8 b = glb_bfrag(W1T, 320, w * 128 + n * 16, ks * 32, lane);
            #pragma unroll
            for (int m = 0; m < 4; ++m) acc[m][n] = MFMA16(a[m], b, acc[m][n]);
        }
    }
}

__device__ __forceinline__ void stage_pair_glb(char* P, const bf16* __restrict__ pairG,
                                               int e0, int tid) {
    for (int it = tid; it < 64 * 40; it += 256) {
        int r = it / 40, c = it - r * 40;
        bf16x8 v = *(const bf16x8*)(pairG + (size_t)(e0 + r) * 320 + c * 8);
        *(bf16x8*)(P + r * 640 + ((c * 16) ^ ((r & 7) << 4))) = v;
    }
}

__device__ __forceinline__ void gemm2_half(const char* a1buf, const bf16* __restrict__ W2T,
                                           int w, int lane, int kg0, f32x4 (&acc2)[4][4]) {
    #pragma unroll 2
    for (int ks = 0; ks < 8; ++ks) {
        bf16x8 a[4];
        #pragma unroll
        for (int m = 0; m < 4; ++m) a[m] = lds_afrag(a1buf, 256, m * 16, ks * 32, lane);
        #pragma unroll
        for (int n = 0; n < 4; ++n) {
            bf16x8 b = glb_bfrag(W2T, 512, w * 64 + n * 16, kg0 + ks * 32, lane);
            #pragma unroll
            for (int m = 0; m < 4; ++m) acc2[m][n] = MFMA16(a[m], b, acc2[m][n]);
        }
    }
}

// GEMM1(chunked) -> bn1 -> a1(Q) -> GEMM2 split-K. P = pair tile, Q = 32KB a1 buffer.
__device__ __forceinline__ void gemm12(const char* P, char* Q,
                                       const bf16* __restrict__ W1T, const float* __restrict__ b1,
                                       const bf16* __restrict__ W2T,
                                       const float* __restrict__ scale1, const float* __restrict__ shift1,
                                       int w, int lane, f32x4 (&acc2)[4][4]) {
    #pragma unroll
    for (int m = 0; m < 4; ++m)
        #pragma unroll
        for (int n = 0; n < 4; ++n) acc2[m][n] = (f32x4){0.f, 0.f, 0.f, 0.f};

    #pragma unroll
    for (int half = 0; half < 2; ++half) {
        #pragma unroll
        for (int chunk = 0; chunk < 2; ++chunk) {
            int lcol = w * 64 + chunk * 32;        // col within a1buf [0,256)
            int gbase = half * 256 + lcol;         // h1 column
            f32x4 acc1[4][2];
            gemm1_chunk(P, W1T, gbase, lane, acc1);
            #pragma unroll
            for (int n = 0; n < 2; ++n) {
                int lc = lcol + n * 16 + (lane & 15);
                int gc = half * 256 + lc;
                float bb = b1[gc], sc = scale1[gc], sh = shift1[gc];
                #pragma unroll
                for (int m = 0; m < 4; ++m)
                    #pragma unroll
                    for (int rr = 0; rr < 4; ++rr) {
                        int row = m * 16 + ((lane >> 4) << 2) + rr;
                        float a = fmaxf(fmaf(acc1[m][n][rr] + bb, sc, sh), 0.f);
                        *(bf16*)(Q + row * 512 + ((lc * 2) ^ ((row & 7) << 4))) = (bf16)a;
                    }
            }
        }
        __syncthreads();
        gemm2_half(Q, W2T, w, lane, half * 256, acc2);
        __syncthreads();
    }
}

// GEMM3..6 tail; expects a2 [64][256] bf16 swizzled at Q+0. Uses Q up to 24704 B.
__device__ __forceinline__ void mlp_tail(char* smem,
                                         const bf16* __restrict__ W3T, const float* __restrict__ b3,
                                         const bf16* __restrict__ W4T, const float* __restrict__ b4,
                                         const bf16* __restrict__ W5T, const float* __restrict__ b5,
                                         const float* __restrict__ W6, const float* __restrict__ b6,
                                         float* __restrict__ out, int E, int e0,
                                         int tid, int lane, int w) {
    // GEMM3: [64][256] @ [256][128]
    f32x4 acc3[4][2];
    #pragma unroll
    for (int m = 0; m < 4; ++m)
        #pragma unroll
        for (int n = 0; n < 2; ++n) acc3[m][n] = (f32x4){0.f, 0.f, 0.f, 0.f};
    for (int ks = 0; ks < 8; ++ks) {
        bf16x8 a[4];
        #pragma unroll
        for (int m = 0; m < 4; ++m) a[m] = lds_afrag(smem, 256, m * 16, ks * 32, lane);
        #pragma unroll
        for (int n = 0; n < 2; ++n) {
            bf16x8 b = glb_bfrag(W3T, 256, w * 32 + n * 16, ks * 32, lane);
            #pragma unroll
            for (int m = 0; m < 4; ++m) acc3[m][n] = MFMA16(a[m], b, acc3[m][n]);
        }
    }
    __syncthreads();
    if (tid < 32) ((float*)(smem + 24576))[tid] = W6[tid];  // region dead now
    #pragma unroll
    for (int n = 0; n < 2; ++n) {
        int col = w * 32 + n * 16 + (lane & 15);
        float bb = b3[col];
        #pragma unroll
        for (int m = 0; m < 4; ++m)
            #pragma unroll
            for (int rr = 0; rr < 4; ++rr) {
                int row = m * 16 + ((lane >> 4) << 2) + rr;
                float a = fmaxf(acc3[m][n][rr] + bb, 0.f);
                *(bf16*)(smem + row * 256 + ((col * 2) ^ ((row & 7) << 4))) = (bf16)a;
            }
    }
    __syncthreads();

    // GEMM4: [64][128] @ [128][64]
    f32x4 acc4[4];
    #pragma unroll
    for (int m = 0; m < 4; ++m) acc4[m] = (f32x4){0.f, 0.f, 0.f, 0.f};
    for (int ks = 0; ks < 4; ++ks) {
        bf16x8 a[4];
        #pragma unroll
        for (int m = 0; m < 4; ++m) a[m] = lds_afrag(smem, 128, m * 16, ks * 32, lane);
        bf16x8 b = glb_bfrag(W4T, 128, w * 16, ks * 32, lane);
        #pragma unroll
        for (int m = 0; m < 4; ++m) acc4[m] = MFMA16(a[m], b, acc4[m]);
    }
    __syncthreads();
    {
        int col = w * 16 + (lane & 15);
        float bb = b4[col];
        #pragma unroll
        for (int m = 0; m < 4; ++m)
            #pragma unroll
            for (int rr = 0; rr < 4; ++rr) {
                int row = m * 16 + ((lane >> 4) << 2) + rr;
                float a = fmaxf(acc4[m][rr] + bb, 0.f);
                *(bf16*)(smem + row * 128 + ((col * 2) ^ ((row & 7) << 4))) = (bf16)a;
            }
    }
    __syncthreads();

    // GEMM5: [64][64] @ [64][32] -> a5 f32 at smem+16384 (waves 0,1)
    if (w < 2) {
        f32x4 acc5[4];
        #pragma unroll
        for (int m = 0; m < 4; ++m) acc5[m] = (f32x4){0.f, 0.f, 0.f, 0.f};
        for (int ks = 0; ks < 2; ++ks) {
            bf16x8 a[4];
            #pragma unroll
            for (int m = 0; m < 4; ++m) a[m] = lds_afrag(smem, 64, m * 16, ks * 32, lane);
            bf16x8 b = glb_bfrag(W5T, 64, w * 16, ks * 32, lane);
            #pragma unroll
            for (int m = 0; m < 4; ++m) acc5[m] = MFMA16(a[m], b, acc5[m]);
        }
        int col = w * 16 + (lane & 15);
        float bb = b5[col];
        float* a5f = (float*)(smem + 16384);
        #pragma unroll
        for (int m = 0; m < 4; ++m)
            #pragma unroll
            for (int rr = 0; rr < 4; ++rr) {
                int row = m * 16 + ((lane >> 4) << 2) + rr;
                a5f[row * 32 + col] = fmaxf(acc5[m][rr] + bb, 0.f);
            }
    }
    __syncthreads();

    if (tid < 64) {
        int ge = e0 + tid;
        if (ge < E) {
            const float* a5f = (const float*)(smem + 16384) + tid * 32;
            const float* w6 = (const float*)(smem + 24576);
            float s = b6[0];
            #pragma unroll
            for (int k = 0; k < 32; ++k) {
                int kk = (k + tid) & 31;
                s = fmaf(a5f[kk], w6[kk], s);
            }
            out[ge] = s;
        }
    }
}

// ---------------- tier-1 phase kernels ----------------

// Phase A: gather pair (bf16 nodes) -> LDS + pairG, chunked GEMM1, stats1.
__global__ __launch_bounds__(256, 3)
void k_mlpA(const bf16* __restrict__ xb2B, const int* __restrict__ ei, const float* __restrict__ ef,
            const bf16* __restrict__ W1T, const float* __restrict__ b1,
            float* __restrict__ sum1, float* __restrict__ sq1,
            bf16* __restrict__ pairG, int E) {
    __shared__ char smem[40960];
    const int tid = threadIdx.x, lane = tid & 63, w = tid >> 6;
    const int e0 = blockIdx.x * 64;
    const int* src = ei;
    const int* dst = ei + E;

    for (int it = tid; it < 64 * 40; it += 256) {
        int r = it / 40, c = it - r * 40;
        int ge = e0 + r;
        bf16x8 v;
        if (ge < E) {
            if (c < 16)      v = *(const bf16x8*)(xb2B + (size_t)src[ge] * 128 + c * 8);
            else if (c < 32) v = *(const bf16x8*)(xb2B + (size_t)dst[ge] * 128 + (c - 16) * 8);
            else {
                const float* p = ef + (size_t)ge * 64 + (c - 32) * 8;
                v = to_bf16x8(*(const float4*)p, *(const float4*)(p + 4));
            }
        } else {
            v = zero_bf16x8();
        }
        *(bf16x8*)(smem + r * 640 + ((c * 16) ^ ((r & 7) << 4))) = v;
        *(bf16x8*)(pairG + (size_t)ge * 320 + c * 8) = v;
    }
    __syncthreads();

    #pragma unroll
    for (int chunk = 0; chunk < 4; ++chunk) {
        int cbase = w * 128 + chunk * 32;
        f32x4 acc[4][2];
        gemm1_chunk(smem, W1T, cbase, lane, acc);
        #pragma unroll
        for (int n = 0; n < 2; ++n) {
            int col = cbase + n * 16 + (lane & 15);
            float bb = b1[col];
            float s = 0.f, q = 0.f;
            #pragma unroll
            for (int m = 0; m < 4; ++m)
                #pragma unroll
                for (int rr = 0; rr < 4; ++rr) {
                    int row = m * 16 + ((lane >> 4) << 2) + rr;
                    if (e0 + row < E) {
                        float h = acc[m][n][rr] + bb;
                        s += h; q += h * h;
                    }
                }
            s += __shfl_xor(s, 16); s += __shfl_xor(s, 32);
            q += __shfl_xor(q, 16); q += __shfl_xor(q, 32);
            if (lane < 16) { atomicAdd(&sum1[col], s); atomicAdd(&sq1[col], q); }
        }
    }
}

// Phase B: pairG -> GEMM1(chunked)+bn1 -> GEMM2 -> stats2
__global__ __launch_bounds__(256, 2)
void k_mlpB(const bf16* __restrict__ pairG,
            const bf16* __restrict__ W1T, const float* __restrict__ b1,
            const bf16* __restrict__ W2T, const float* __restrict__ b2,
            const float* __restrict__ scale1, const float* __restrict__ shift1,
            float* __restrict__ sum2, float* __restrict__ sq2, int E) {
    __shared__ char smem[40960 + 32768];
    char* P = smem;
    char* Q = smem + 40960;
    const int tid = threadIdx.x, lane = tid & 63, w = tid >> 6;
    const int e0 = blockIdx.x * 64;

    stage_pair_glb(P, pairG, e0, tid);
    __syncthreads();

    f32x4 acc2[4][4];
    gemm12(P, Q, W1T, b1, W2T, scale1, shift1, w, lane, acc2);

    const int cb2 = w * 64;
    #pragma unroll
    for (int n = 0; n < 4; ++n) {
        int col = cb2 + n * 16 + (lane & 15);
        float bb = b2[col];
        float s = 0.f, q = 0.f;
        #pragma unroll
        for (int m = 0; m < 4; ++m)
            #pragma unroll
            for (int rr = 0; rr < 4; ++rr) {
                int row = m * 16 + ((lane >> 4) << 2) + rr;
                if (e0 + row < E) {
                    float h = acc2[m][n][rr] + bb;
                    s += h; q += h * h;
                }
            }
        s += __shfl_xor(s, 16); s += __shfl_xor(s, 32);
        q += __shfl_xor(q, 16); q += __shfl_xor(q, 32);
        if (lane < 16) { atomicAdd(&sum2[col], s); atomicAdd(&sq2[col], q); }
    }
}

// Phase C: pairG -> GEMM1+bn1 -> GEMM2 -> bn2 -> GEMM3..6 -> out
__global__ __launch_bounds__(256, 2)
void k_mlpC(const bf16* __restrict__ pairG,
            const bf16* __restrict__ W1T, const float* __restrict__ b1,
            const bf16* __restrict__ W2T, const float* __restrict__ b2,
            const bf16* __restrict__ W3T, const float* __restrict__ b3,
            const bf16* __restrict__ W4T, const float* __restrict__ b4,
            const bf16* __restrict__ W5T, const float* __restrict__ b5,
            const float* __restrict__ W6, const float* __restrict__ b6,
            const float* __restrict__ scale1, const float* __restrict__ shift1,
            const float* __restrict__ scale2, const float* __restrict__ shift2,
            float* __restrict__ out, int E) {
    __shared__ char smem[40960 + 32768];
    char* P = smem;
    char* Q = smem + 40960;
    const int tid = threadIdx.x, lane = tid & 63, w = tid >> 6;
    const int e0 = blockIdx.x * 64;

    stage_pair_glb(P, pairG, e0, tid);
    __syncthreads();

    f32x4 acc2[4][4];
    gemm12(P, Q, W1T, b1, W2T, scale1, shift1, w, lane, acc2);
    // last gemm2_half was followed by a barrier; Q is dead -> write a2 there
    const int cb2 = w * 64;
    #pragma unroll
    for (int n = 0; n < 4; ++n) {
        int col = cb2 + n * 16 + (lane & 15);
        float bb = b2[col], sc = scale2[col], sh = shift2[col];
        #pragma unroll
        for (int m = 0; m < 4; ++m)
            #pragma unroll
            for (int rr = 0; rr < 4; ++rr) {
                int row = m * 16 + ((lane >> 4) << 2) + rr;
                float a = fmaxf(fmaf(acc2[m][n][rr] + bb, sc, sh), 0.f);
                *(bf16*)(Q + row * 512 + ((col * 2) ^ ((row & 7) << 4))) = (bf16)a;
            }
    }
    __syncthreads();

    mlp_tail(Q, W3T, b3, W4T, b4, W5T, b5, W6, b6, out, E, e0, tid, lane, w);
}

// ---------------- T0 fallback: fused edge MLP (3 gather passes, proven R1) ----------------
template <int PASS>
__global__ __launch_bounds__(256, 2)
void k_mlp(const float* __restrict__ x, const int* __restrict__ ei, const float* __restrict__ ef,
           const bf16* __restrict__ W1T, const float* __restrict__ b1,
           const bf16* __restrict__ W2T, const float* __restrict__ b2,
           const bf16* __restrict__ W3T, const float* __restrict__ b3,
           const bf16* __restrict__ W4T, const float* __restrict__ b4,
           const bf16* __restrict__ W5T, const float* __restrict__ b5,
           const float* __restrict__ W6, const float* __restrict__ b6,
           const float* __restrict__ scale1, const float* __restrict__ shift1,
           const float* __restrict__ scale2, const float* __restrict__ shift2,
           float* __restrict__ sum1, float* __restrict__ sq1,
           float* __restrict__ sum2, float* __restrict__ sq2,
           float* __restrict__ out, int E) {
    __shared__ char smem[65536];
    const int tid = threadIdx.x, lane = tid & 63, w = tid >> 6;
    const int e0 = blockIdx.x * 64;
    const int* src = ei;
    const int* dst = ei + E;

    for (int it = tid; it < 64 * 40; it += 256) {
        int r = it / 40, c = it - r * 40;
        int ge = e0 + r;
        float4 fa = {0, 0, 0, 0}, fb = {0, 0, 0, 0};
        if (ge < E) {
            int base = c * 8;
            const float* p;
            if (base < 128)      p = x + (size_t)src[ge] * 128 + base;
            else if (base < 256) p = x + (size_t)dst[ge] * 128 + (base - 128);
            else                 p = ef + (size_t)ge * 64 + (base - 256);
            fa = *(const float4*)p;
            fb = *(const float4*)(p + 4);
        }
        bf16x8 v = to_bf16x8(fa, fb);
        *(bf16x8*)(smem + r * 640 + ((c * 16) ^ ((r & 7) << 4))) = v;
    }
    __syncthreads();

    f32x4 acc[4][8];
    run_gemm1(smem, W1T, w, lane, acc);
    const int cb = w * 128;

    if (PASS == 0) {
        #pragma unroll
        for (int n = 0; n < 8; ++n) {
            int col = cb + n * 16 + (lane & 15);
            float bb = b1[col];
            float s = 0.f, q = 0.f;
            #pragma unroll
            for (int m = 0; m < 4; ++m)
                #pragma unroll
                for (int rr = 0; rr < 4; ++rr) {
                    int row = m * 16 + ((lane >> 4) << 2) + rr;
                    if (e0 + row < E) {
                        float h = acc[m][n][rr] + bb;
                        s += h; q += h * h;
                    }
                }
            s += __shfl_xor(s, 16); s += __shfl_xor(s, 32);
            q += __shfl_xor(q, 16); q += __shfl_xor(q, 32);
            if (lane < 16) { atomicAdd(&sum1[col], s); atomicAdd(&sq1[col], q); }
        }
        return;
    }

    __syncthreads();
    #pragma unroll
    for (int n = 0; n < 8; ++n) {
        int col = cb + n * 16 + (lane & 15);
        float bb = b1[col], sc = scale1[col], sh = shift1[col];
        #pragma unroll
        for (int m = 0; m < 4; ++m)
            #pragma unroll
            for (int rr = 0; rr < 4; ++rr) {
                int row = m * 16 + ((lane >> 4) << 2) + rr;
                float a = fmaxf(fmaf(acc[m][n][rr] + bb, sc, sh), 0.f);
                *(bf16*)(smem + row * 1024 + ((col * 2) ^ ((row & 7) << 4))) = (bf16)a;
            }
    }
    __syncthreads();

    f32x4 acc2[4][4];
    #pragma unroll
    for (int m = 0; m < 4; ++m)
        #pragma unroll
        for (int n = 0; n < 4; ++n) acc2[m][n] = (f32x4){0.f, 0.f, 0.f, 0.f};
    #pragma unroll 2
    for (int ks = 0; ks < 16; ++ks) {
        bf16x8 a[4];
        #pragma unroll
        for (int m = 0; m < 4; ++m) a[m] = lds_afrag(smem, 512, m * 16, ks * 32, lane);
        #pragma unroll
        for (int n = 0; n < 4; ++n) {
            bf16x8 b = glb_bfrag(W2T, 512, w * 64 + n * 16, ks * 32, lane);
            #pragma unroll
            for (int m = 0; m < 4; ++m) acc2[m][n] = MFMA16(a[m], b, acc2[m][n]);
        }
    }
    const int cb2 = w * 64;

    if (PASS == 1) {
        #pragma unroll
        for (int n = 0; n < 4; ++n) {
            int col = cb2 + n * 16 + (lane & 15);
            float bb = b2[col];
            float s = 0.f, q = 0.f;
            #pragma unroll
            for (int m = 0; m < 4; ++m)
                #pragma unroll
                for (int rr = 0; rr < 4; ++rr) {
                    int row = m * 16 + ((lane >> 4) << 2) + rr;
                    if (e0 + row < E) {
                        float h = acc2[m][n][rr] + bb;
                        s += h; q += h * h;
                    }
                }
            s += __shfl_xor(s, 16); s += __shfl_xor(s, 32);
            q += __shfl_xor(q, 16); q += __shfl_xor(q, 32);
            if (lane < 16) { atomicAdd(&sum2[col], s); atomicAdd(&sq2[col], q); }
        }
        return;
    }

    __syncthreads();
    if (tid < 32) *(float*)(smem + 49152 + tid * 4) = W6[tid];
    #pragma unroll
    for (int n = 0; n < 4; ++n) {
        int col = cb2 + n * 16 + (lane & 15);
        float bb = b2[col], sc = scale2[col], sh = shift2[col];
        #pragma unroll
        for (int m = 0; m < 4; ++m)
            #pragma unroll
            for (int rr = 0; rr < 4; ++rr) {
                int row = m * 16 + ((lane >> 4) << 2) + rr;
                float a = fmaxf(fmaf(acc2[m][n][rr] + bb, sc, sh), 0.f);
                *(bf16*)(smem + row * 512 + ((col * 2) ^ ((row & 7) << 4))) = (bf16)a;
            }
    }
    __syncthreads();

    f32x4 acc3[4][2];
    #pragma unroll
    for (int m = 0; m < 4; ++m)
        #pragma unroll
        for (int n = 0; n < 2; ++n) acc3[m][n] = (f32x4){0.f, 0.f, 0.f, 0.f};
    for (int ks = 0; ks < 8; ++ks) {
        bf16x8 a[4];
        #pragma unroll
        for (int m = 0; m < 4; ++m) a[m] = lds_afrag(smem, 256, m * 16, ks * 32, lane);
        #pragma unroll
        for (int n = 0; n < 2; ++n) {
            bf16x8 b = glb_bfrag(W3T, 256, w * 32 + n * 16, ks * 32, lane);
            #pragma unroll
            for (int m = 0; m < 4; ++m) acc3[m][n] = MFMA16(a[m], b, acc3[m][n]);
        }
    }
    __syncthreads();
    #pragma unroll
    for (int n = 0; n < 2; ++n) {
        int col = w * 32 + n * 16 + (lane & 15);
        float bb = b3[col];
        #pragma unroll
        for (int m = 0; m < 4; ++m)
            #pragma unroll
            for (int rr = 0; rr < 4; ++rr) {
                int row = m * 16 + ((lane >> 4) << 2) + rr;
                float a = fmaxf(acc3[m][n][rr] + bb, 0.f);
                *(bf16*)(smem + row * 256 + ((col * 2) ^ ((row & 7) << 4))) = (bf16)a;
            }
    }
    __syncthreads();

    f32x4 acc4[4];
    #pragma unroll
    for (int m = 0; m < 4; ++m) acc4[m] = (f32x4){0.f, 0.f, 0.f, 0.f};
    for (int ks = 0; ks < 4; ++ks) {
        bf16x8 a[4];
        #pragma unroll
        for (int m = 0; m < 4; ++m) a[m] = lds_afrag(smem, 128, m * 16, ks * 32, lane);
        bf16x8 b = glb_bfrag(W4T, 128, w * 16, ks * 32, lane);
        #pragma unroll
        for (int m = 0; m < 4; ++m) acc4[m] = MFMA16(a[m], b, acc4[m]);
    }
    __syncthreads();
    {
        int col = w * 16 + (lane & 15);
        float bb = b4[col];
        #pragma unroll
        for (int m = 0; m < 4; ++m)
            #pragma unroll
            for (int rr = 0; rr < 4; ++rr) {
                int row = m * 16 + ((lane >> 4) << 2) + rr;
                float a = fmaxf(acc4[m][rr] + bb, 0.f);
                *(bf16*)(smem + row * 128 + ((col * 2) ^ ((row & 7) << 4))) = (bf16)a;
            }
    }
    __syncthreads();

    if (w < 2) {
        f32x4 acc5[4];
        #pragma unroll
        for (int m = 0; m < 4; ++m) acc5[m] = (f32x4){0.f, 0.f, 0.f, 0.f};
        for (int ks = 0; ks < 2; ++ks) {
            bf16x8 a[4];
            #pragma unroll
            for (int m = 0; m < 4; ++m) a[m] = lds_afrag(smem, 64, m * 16, ks * 32, lane);
            bf16x8 b = glb_bfrag(W5T, 64, w * 16, ks * 32, lane);
            #pragma unroll
            for (int m = 0; m < 4; ++m) acc5[m] = MFMA16(a[m], b, acc5[m]);
        }
        int col = w * 16 + (lane & 15);
        float bb = b5[col];
        float* a5f = (float*)(smem + 16384);
        #pragma unroll
        for (int m = 0; m < 4; ++m)
            #pragma unroll
            for (int rr = 0; rr < 4; ++rr) {
                int row = m * 16 + ((lane >> 4) << 2) + rr;
                a5f[row * 32 + col] = fmaxf(acc5[m][rr] + bb, 0.f);
            }
    }
    __syncthreads();

    if (tid < 64) {
        int ge = e0 + tid;
        if (ge < E) {
            const float* a5f = (const float*)(smem + 16384) + tid * 32;
            const float* w6 = (const float*)(smem + 49152);
            float s = b6[0];
            #pragma unroll
            for (int k = 0; k < 32; ++k) {
                int kk = (k + tid) & 31;
                s = fmaf(a5f[kk], w6[kk], s);
            }
            out[ge] = s;
        }
    }
}

// ---------------- launch ----------------

extern "C" void kernel_launch(void* const* d_in, const int* in_sizes, int n_in,
                              void* d_out, int out_size, void* d_ws, size_t ws_size,
                              hipStream_t stream) {
    const float* x      = (const float*)d_in[0];
    const int*   ei     = (const int*)d_in[1];
    const float* ef     = (const float*)d_in[2];
    const float* W_nb   = (const float*)d_in[4];
    const float* b_nb   = (const float*)d_in[5];
    const float* W_self = (const float*)d_in[6];
    const float* b_self = (const float*)d_in[7];
    const float* W1 = (const float*)d_in[8];  const float* b1 = (const float*)d_in[9];
    const float* W2 = (const float*)d_in[10]; const float* b2 = (const float*)d_in[11];
    const float* W3 = (const float*)d_in[12]; const float* b3 = (const float*)d_in[13];
    const float* W4 = (const float*)d_in[14]; const float* b4 = (const float*)d_in[15];
    const float* W5 = (const float*)d_in[16]; const float* b5 = (const float*)d_in[17];
    const float* W6 = (const float*)d_in[18]; const float* b6 = (const float*)d_in[19];
    const float* g1 = (const float*)d_in[20]; const float* beta1 = (const float*)d_in[21];
    const float* g2 = (const float*)d_in[22]; const float* beta2 = (const float*)d_in[23];

    const int N = in_sizes[0] / 128;
    const int E = in_sizes[1] / 2;
    const int mlpGrid = (E + 63) / 64;
    const size_t Epad = (size_t)mlpGrid * 64;

    char* ws = (char*)d_ws;
    size_t off = 0;
    auto alloc = [&](size_t bytes) {
        size_t o = off;
        off = (off + bytes + 255) & ~(size_t)255;
        return o;
    };
    size_t oDeg = alloc((size_t)N * 4);
    size_t oCur = alloc((size_t)N * 4);
    size_t oSum1 = alloc(512 * 4), oSq1 = alloc(512 * 4);
    size_t oSum2 = alloc(256 * 4), oSq2 = alloc(256 * 4);
    size_t zeroEnd = off;
    size_t oOff = alloc((size_t)(N + 1) * 4);
    size_t oInv = alloc((size_t)N * 4);
    size_t oEid = alloc((size_t)E * 4);
    size_t oSm  = alloc((size_t)N * 192 * 4);
    size_t oXb1 = alloc((size_t)N * 128 * 4);
    size_t oXb2 = alloc((size_t)N * 128 * 4);
    size_t oXb2B = alloc((size_t)N * 128 * 2);
    size_t oScale1 = alloc(512 * 4), oShift1 = alloc(512 * 4);
    size_t oScale2 = alloc(256 * 4), oShift2 = alloc(256 * 4);
    size_t oWcat = alloc(128 * 320 * 2);
    size_t oW1T = alloc((size_t)512 * 320 * 2);
    size_t oW2T = alloc((size_t)256 * 512 * 2);
    size_t oW3T = alloc((size_t)128 * 256 * 2);
    size_t oW4T = alloc((size_t)64 * 128 * 2);
    size_t oW5T = alloc((size_t)32 * 64 * 2);
    size_t baseEnd = off;
    size_t oPair = alloc(Epad * 320 * 2);   // bf16 pair tile
    size_t pairEnd = off;

    int mode = (ws_size >= pairEnd) ? 1 : (ws_size >= baseEnd) ? 0 : -1;
    if (mode < 0) return;

    float* deg = (float*)(ws + oDeg);
    unsigned* cursor = (unsigned*)(ws + oCur);
    float* sum1 = (float*)(ws + oSum1); float* sq1 = (float*)(ws + oSq1);
    float* sum2 = (float*)(ws + oSum2); float* sq2 = (float*)(ws + oSq2);
    unsigned* offsets = (unsigned*)(ws + oOff);
    float* invdeg = (float*)(ws + oInv);
    unsigned* eid = (unsigned*)(ws + oEid);
    float* sm  = (float*)(ws + oSm);
    float* xb1 = (float*)(ws + oXb1);
    float* xb2 = (float*)(ws + oXb2);
    bf16* xb2B = (bf16*)(ws + oXb2B);
    float* scale1 = (float*)(ws + oScale1); float* shift1 = (float*)(ws + oShift1);
    float* scale2 = (float*)(ws + oScale2); float* shift2 = (float*)(ws + oShift2);
    bf16* WcatT = (bf16*)(ws + oWcat);
    bf16* W1T = (bf16*)(ws + oW1T);
    bf16* W2T = (bf16*)(ws + oW2T);
    bf16* W3T = (bf16*)(ws + oW3T);
    bf16* W4T = (bf16*)(ws + oW4T);
    bf16* W5T = (bf16*)(ws + oW5T);
    bf16* pairG = (bf16*)(ws + oPair);

    hipMemsetAsync(ws, 0, zeroEnd, stream);

    k_transpose<<<(128 * 128 + 255) / 256, 256, 0, stream>>>(W_self, WcatT, 128, 128, 320, 0);
    k_transpose<<<(192 * 128 + 255) / 256, 256, 0, stream>>>(W_nb, WcatT, 192, 128, 320, 128);
    k_transpose<<<(320 * 512 + 255) / 256, 256, 0, stream>>>(W1, W1T, 320, 512, 320, 0);
    k_transpose<<<(512 * 256 + 255) / 256, 256, 0, stream>>>(W2, W2T, 512, 256, 512, 0);
    k_transpose<<<(256 * 128 + 255) / 256, 256, 0, stream>>>(W3, W3T, 256, 128, 256, 0);
    k_transpose<<<(128 * 64 + 255) / 256, 256, 0, stream>>>(W4, W4T, 128, 64, 128, 0);
    k_transpose<<<(64 * 32 + 255) / 256, 256, 0, stream>>>(W5, W5T, 64, 32, 64, 0);

    const int* dst = ei + E;
    k_deg<<<(E + 255) / 256, 256, 0, stream>>>(dst, deg, E);
    k_scan<<<1, 1024, 0, stream>>>(deg, offsets, invdeg, N);
    k_scatter<<<(E + 255) / 256, 256, 0, stream>>>(dst, offsets, cursor, eid, E);

    // conv layer 1 (f32 out), conv layer 2 (bf16 out for T1, f32 for T0)
    k_agg<<<(N + 15) / 16, 256, 0, stream>>>(x, ef, ei, offsets, invdeg, eid, sm, N);
    k_nodegemm<0><<<(N + 63) / 64, 256, 0, stream>>>(x, sm, WcatT, b_self, b_nb, offsets, xb1, nullptr, N);
    k_agg<<<(N + 15) / 16, 256, 0, stream>>>(xb1, ef, ei, offsets, invdeg, eid, sm, N);

    const float invE = 1.0f / (float)E;
    if (mode == 1) {
        k_nodegemm<1><<<(N + 63) / 64, 256, 0, stream>>>(xb1, sm, WcatT, b_self, b_nb, offsets, nullptr, xb2B, N);
        k_mlpA<<<mlpGrid, 256, 0, stream>>>(xb2B, ei, ef, W1T, b1, sum1, sq1, pairG, E);
        k_finalize<<<2, 256, 0, stream>>>(sum1, sq1, g1, beta1, scale1, shift1, 512, invE);
        k_mlpB<<<mlpGrid, 256, 0, stream>>>(pairG, W1T, b1, W2T, b2, scale1, shift1, sum2, sq2, E);
        k_finalize<<<1, 256, 0, stream>>>(sum2, sq2, g2, beta2, scale2, shift2, 256, invE);
        k_mlpC<<<mlpGrid, 256, 0, stream>>>(pairG, W1T, b1, W2T, b2, W3T, b3, W4T, b4,
                                            W5T, b5, W6, b6, scale1, shift1,
                                            scale2, shift2, (float*)d_out, E);
    } else {
        k_nodegemm<0><<<(N + 63) / 64, 256, 0, stream>>>(xb1, sm, WcatT, b_self, b_nb, offsets, xb2, nullptr, N);
        k_mlp<0><<<mlpGrid, 256, 0, stream>>>(xb2, ei, ef, W1T, b1, W2T, b2, W3T, b3, W4T, b4,
                                              W5T, b5, W6, b6, scale1, shift1, scale2, shift2,
                                              sum1, sq1, sum2, sq2, (float*)d_out, E);
        k_finalize<<<2, 256, 0, stream>>>(sum1, sq1, g1, beta1, scale1, shift1, 512, invE);
        k_mlp<1><<<mlpGrid, 256, 0, stream>>>(xb2, ei, ef, W1T, b1, W2T, b2, W3T, b3, W4T, b4,
                                              W5T, b5, W6, b6, scale1, shift1, scale2, shift2,
                                              sum1, sq1, sum2, sq2, (float*)d_out, E);
        k_finalize<<<1, 256, 0, stream>>>(sum2, sq2, g2, beta2, scale2, shift2, 256, invE);
        k_mlp<2><<<mlpGrid, 256, 0, stream>>>(xb2, ei, ef, W1T, b1, W2T, b2, W3T, b3, W4T, b4,
                                              W5T, b5, W6, b6, scale1, shift1, scale2, shift2,
                                              sum1, sq1, sum2, sq2, (float*)d_out, E);
    }
}

// Round 5
// 3213.214 us; speedup vs baseline: 1.8803x; 1.0028x over previous
//
#include <hip/hip_runtime.h>

using bf16 = __bf16;
typedef bf16 bf16x8 __attribute__((ext_vector_type(8)));
typedef float f32x4 __attribute__((ext_vector_type(4)));

#define MFMA16(a, b, c) __builtin_amdgcn_mfma_f32_16x16x32_bf16(a, b, c, 0, 0, 0)

// ---------------- helpers ----------------

__device__ __forceinline__ bf16x8 to_bf16x8(float4 a, float4 b) {
    bf16x8 v;
    v[0] = (bf16)a.x; v[1] = (bf16)a.y; v[2] = (bf16)a.z; v[3] = (bf16)a.w;
    v[4] = (bf16)b.x; v[5] = (bf16)b.y; v[6] = (bf16)b.z; v[7] = (bf16)b.w;
    return v;
}

__device__ __forceinline__ bf16x8 zero_bf16x8() {
    bf16 z = (bf16)0.f;
    bf16x8 v = {z, z, z, z, z, z, z, z};
    return v;
}

// A-fragment from a swizzled row-major LDS tile [rows][ldK] bf16.
// Swizzle: byte_off_in_row ^= ((row&7)<<4). Requires ldK*2 % 128 == 0.
__device__ __forceinline__ bf16x8 lds_afrag(const char* smem, int ldK, int mbase, int kbase, int lane) {
    int r = mbase + (lane & 15);
    int off = (kbase + ((lane >> 4) << 3)) << 1;
    off ^= (r & 7) << 4;
    return *(const bf16x8*)(smem + r * (ldK << 1) + off);
}

// B-fragment from global WT[N][K] bf16 (i.e., W transposed): 8 contiguous k at row n.
__device__ __forceinline__ bf16x8 glb_bfrag(const bf16* __restrict__ WT, int K, int nbase, int kbase, int lane) {
    int n = nbase + (lane & 15);
    int k = kbase + ((lane >> 4) << 3);
    return *(const bf16x8*)(WT + (size_t)n * K + k);
}

// ---------------- small kernels ----------------

__global__ void k_transpose(const float* __restrict__ W, bf16* __restrict__ WT,
                            int K, int N, int ldT, int k0) {
    int idx = blockIdx.x * 256 + threadIdx.x;
    if (idx < K * N) {
        int k = idx / N, n = idx - k * N;
        WT[(size_t)n * ldT + k0 + k] = (bf16)W[idx];
    }
}

__global__ void k_deg(const int* __restrict__ dst, float* __restrict__ deg, int E) {
    int e = blockIdx.x * 256 + threadIdx.x;
    if (e < E) atomicAdd(&deg[dst[e]], 1.0f);
}

__global__ void k_scan(const float* __restrict__ deg, unsigned* __restrict__ offsets,
                       float* __restrict__ invdeg, int N) {
    __shared__ unsigned wsum[16];
    __shared__ unsigned carry_s, tot_s;
    const int tid = threadIdx.x, lane = tid & 63, wid = tid >> 6;
    if (tid == 0) carry_s = 0;
    __syncthreads();
    for (int base = 0; base < N; base += 1024) {
        int i = base + tid;
        unsigned v = (i < N) ? (unsigned)deg[i] : 0u;
        unsigned inc = v;
        #pragma unroll
        for (int d = 1; d < 64; d <<= 1) {
            unsigned t = (unsigned)__shfl_up((int)inc, d, 64);
            if (lane >= d) inc += t;
        }
        if (lane == 63) wsum[wid] = inc;
        __syncthreads();
        if (wid == 0) {
            unsigned wv = (lane < 16) ? wsum[lane] : 0u;
            unsigned winc = wv;
            #pragma unroll
            for (int d = 1; d < 16; d <<= 1) {
                unsigned t = (unsigned)__shfl_up((int)winc, d, 16);
                if ((lane & 15) >= d) winc += t;
            }
            if (lane < 16) wsum[lane] = winc - wv;
            if (lane == 15) tot_s = winc;
        }
        __syncthreads();
        if (i < N) {
            offsets[i] = carry_s + wsum[wid] + (inc - v);
            invdeg[i] = 1.0f / fmaxf(deg[i], 1.0f);
        }
        __syncthreads();
        if (tid == 0) carry_s += tot_s;
        __syncthreads();
    }
    if (tid == 0) offsets[N] = carry_s;
}

__global__ void k_scatter(const int* __restrict__ dst, const unsigned* __restrict__ offsets,
                          unsigned* __restrict__ cursor, unsigned* __restrict__ eid, int E) {
    int e = blockIdx.x * 256 + threadIdx.x;
    if (e < E) {
        int d = dst[e];
        unsigned p = atomicAdd(&cursor[d], 1u);
        eid[offsets[d] + p] = (unsigned)e;
    }
}

__global__ __launch_bounds__(256)
void k_agg(const float* __restrict__ xin, const float* __restrict__ ef, const int* __restrict__ src,
           const unsigned* __restrict__ offsets, const float* __restrict__ invdeg,
           const unsigned* __restrict__ eid, float* __restrict__ sm, int N) {
    const int lane = threadIdx.x & 63, w = threadIdx.x >> 6;
    int nb = blockIdx.x * 16 + w * 4;
    for (int j = 0; j < 4; ++j) {
        int n = nb + j;
        if (n >= N) return;
        unsigned o0 = offsets[n], o1 = offsets[n + 1];
        float s0 = 0.f, s1 = 0.f, s2 = 0.f;
        for (unsigned t = o0; t < o1; ++t) {
            int e = (int)eid[t];
            int v = src[e];
            s0 += xin[(size_t)v * 128 + lane];
            s1 += xin[(size_t)v * 128 + 64 + lane];
            s2 += ef[(size_t)e * 64 + lane];
        }
        float g = invdeg[n];
        sm[(size_t)n * 192 + lane] = s0 * g;
        sm[(size_t)n * 192 + 64 + lane] = s1 * g;
        sm[(size_t)n * 192 + 128 + lane] = s2 * g;
    }
}

// x_out = relu(concat(x, sm) @ Wcat + b_self + (deg>0 ? b_nb : 0))
template <int BF16OUT>
__global__ __launch_bounds__(256)
void k_nodegemm(const float* __restrict__ xin, const float* __restrict__ sm,
                const bf16* __restrict__ WcatT,
                const float* __restrict__ b_self, const float* __restrict__ b_nb,
                const unsigned* __restrict__ offsets,
                float* __restrict__ xout, bf16* __restrict__ xoutB, int N) {
    __shared__ char smem[64 * 320 * 2];
    const int tid = threadIdx.x, lane = tid & 63, w = tid >> 6;
    const int n0 = blockIdx.x * 64;
    for (int it = tid; it < 64 * 40; it += 256) {
        int r = it / 40, c = it - r * 40;
        int node = n0 + r;
        float4 fa = {0, 0, 0, 0}, fb = {0, 0, 0, 0};
        if (node < N) {
            int base = c * 8;
            const float* p = (base < 128) ? xin + (size_t)node * 128 + base
                                          : sm + (size_t)node * 192 + (base - 128);
            fa = *(const float4*)p;
            fb = *(const float4*)(p + 4);
        }
        bf16x8 v = to_bf16x8(fa, fb);
        *(bf16x8*)(smem + r * 640 + ((c * 16) ^ ((r & 7) << 4))) = v;
    }
    __syncthreads();

    f32x4 acc[4][2];
    #pragma unroll
    for (int m = 0; m < 4; ++m)
        #pragma unroll
        for (int n = 0; n < 2; ++n) acc[m][n] = (f32x4){0.f, 0.f, 0.f, 0.f};

    for (int ks = 0; ks < 10; ++ks) {
        bf16x8 a[4];
        #pragma unroll
        for (int m = 0; m < 4; ++m) a[m] = lds_afrag(smem, 320, m * 16, ks * 32, lane);
        #pragma unroll
        for (int n = 0; n < 2; ++n) {
            bf16x8 b = glb_bfrag(WcatT, 320, w * 32 + n * 16, ks * 32, lane);
            #pragma unroll
            for (int m = 0; m < 4; ++m) acc[m][n] = MFMA16(a[m], b, acc[m][n]);
        }
    }

    #pragma unroll
    for (int n = 0; n < 2; ++n) {
        int col = w * 32 + n * 16 + (lane & 15);
        float bs = b_self[col], bn = b_nb[col];
        #pragma unroll
        for (int m = 0; m < 4; ++m)
            #pragma unroll
            for (int rr = 0; rr < 4; ++rr) {
                int row = m * 16 + ((lane >> 4) << 2) + rr;
                int node = n0 + row;
                if (node < N) {
                    bool hd = offsets[node + 1] > offsets[node];
                    float val = fmaxf(acc[m][n][rr] + bs + (hd ? bn : 0.f), 0.f);
                    if (BF16OUT) xoutB[(size_t)node * 128 + col] = (bf16)val;
                    else         xout[(size_t)node * 128 + col] = val;
                }
            }
    }
}

__global__ void k_finalize(const float* __restrict__ sum, const float* __restrict__ sq,
                           const float* __restrict__ g, const float* __restrict__ beta,
                           float* __restrict__ scale, float* __restrict__ shift,
                           int n, float invE) {
    int i = blockIdx.x * 256 + threadIdx.x;
    if (i < n) {
        float m = sum[i] * invE;
        float v = sq[i] * invE - m * m;
        float sc = g[i] * rsqrtf(v + 1e-5f);
        scale[i] = sc;
        shift[i] = beta[i] - m * sc;
    }
}

// ---------------- shared MLP building blocks ----------------

// GEMM1 over a 32-col chunk: acc[4][2] (keeps register pressure low).
__device__ __forceinline__ void gemm1_chunk(const char* P, const bf16* __restrict__ W1T,
                                            int cbase, int lane, f32x4 (&acc)[4][2]) {
    #pragma unroll
    for (int m = 0; m < 4; ++m)
        #pragma unroll
        for (int n = 0; n < 2; ++n) acc[m][n] = (f32x4){0.f, 0.f, 0.f, 0.f};
    for (int ks = 0; ks < 10; ++ks) {
        bf16x8 a[4];
        #pragma unroll
        for (int m = 0; m < 4; ++m) a[m] = lds_afrag(P, 320, m * 16, ks * 32, lane);
        #pragma unroll
        for (int n = 0; n < 2; ++n) {
            bf16x8 b = glb_bfrag(W1T, 320, cbase + n * 16, ks * 32, lane);
            #pragma unroll
            for (int m = 0; m < 4; ++m) acc[m][n] = MFMA16(a[m], b, acc[m][n]);
        }
    }
}

// full-width GEMM1 (acc[4][8]) for the T0 fallback kernel only ((256,2): no spill)
__device__ __forceinline__ void run_gemm1(const char* smem, const bf16* __restrict__ W1T,
                                          int w, int lane, f32x4 (&acc)[4][8]) {
    #pragma unroll
    for (int m = 0; m < 4; ++m)
        #pragma unroll
        for (int n = 0; n < 8; ++n) acc[m][n] = (f32x4){0.f, 0.f, 0.f, 0.f};
    #pragma unroll 2
    for (int ks = 0; ks < 10; ++ks) {
        bf16x8 a[4];
        #pragma unroll
        for (int m = 0; m < 4; ++m) a[m] = lds_afrag(smem, 320, m * 16, ks * 32, lane);
        #pragma unroll
        for (int n = 0; n < 8; ++n) {
            bf16x8 b = glb_bfrag(W1T, 320, w * 128 + n * 16, ks * 32, lane);
            #pragma unroll
            for (int m = 0; m < 4; ++m) acc[m][n] = MFMA16(a[m], b, acc[m][n]);
        }
    }
}

__device__ __forceinline__ void stage_pair_glb(char* P, const bf16* __restrict__ pairG,
                                               int e0, int tid) {
    for (int it = tid; it < 64 * 40; it += 256) {
        int r = it / 40, c = it - r * 40;
        bf16x8 v = *(const bf16x8*)(pairG + (size_t)(e0 + r) * 320 + c * 8);
        *(bf16x8*)(P + r * 640 + ((c * 16) ^ ((r & 7) << 4))) = v;
    }
}

__device__ __forceinline__ void gemm2_half(const char* a1buf, const bf16* __restrict__ W2T,
                                           int w, int lane, int kg0, f32x4 (&acc2)[4][4]) {
    #pragma unroll 2
    for (int ks = 0; ks < 8; ++ks) {
        bf16x8 a[4];
        #pragma unroll
        for (int m = 0; m < 4; ++m) a[m] = lds_afrag(a1buf, 256, m * 16, ks * 32, lane);
        #pragma unroll
        for (int n = 0; n < 4; ++n) {
            bf16x8 b = glb_bfrag(W2T, 512, w * 64 + n * 16, kg0 + ks * 32, lane);
            #pragma unroll
            for (int m = 0; m < 4; ++m) acc2[m][n] = MFMA16(a[m], b, acc2[m][n]);
        }
    }
}

// stage a [64][256] bf16 tile from hG (row-major, ldH cols) applying bn+relu, swizzled into Q.
__device__ __forceinline__ void stage_bn_half(char* Q, const bf16* __restrict__ hG, int ldH,
                                              int hbase, const float* __restrict__ scale,
                                              const float* __restrict__ shift,
                                              int e0, int tid) {
    for (int it = tid; it < 64 * 32; it += 256) {
        int r = it >> 5, c = it & 31;
        int col0 = hbase + c * 8;
        bf16x8 v = *(const bf16x8*)(hG + (size_t)(e0 + r) * ldH + col0);
        float4 s0 = *(const float4*)(scale + col0);
        float4 s1 = *(const float4*)(scale + col0 + 4);
        float4 h0 = *(const float4*)(shift + col0);
        float4 h1 = *(const float4*)(shift + col0 + 4);
        bf16x8 o;
        o[0] = (bf16)fmaxf(fmaf((float)v[0], s0.x, h0.x), 0.f);
        o[1] = (bf16)fmaxf(fmaf((float)v[1], s0.y, h0.y), 0.f);
        o[2] = (bf16)fmaxf(fmaf((float)v[2], s0.z, h0.z), 0.f);
        o[3] = (bf16)fmaxf(fmaf((float)v[3], s0.w, h0.w), 0.f);
        o[4] = (bf16)fmaxf(fmaf((float)v[4], s1.x, h1.x), 0.f);
        o[5] = (bf16)fmaxf(fmaf((float)v[5], s1.y, h1.y), 0.f);
        o[6] = (bf16)fmaxf(fmaf((float)v[6], s1.z, h1.z), 0.f);
        o[7] = (bf16)fmaxf(fmaf((float)v[7], s1.w, h1.w), 0.f);
        *(bf16x8*)(Q + r * 512 + ((c * 16) ^ ((r & 7) << 4))) = o;
    }
}

// GEMM1(chunked) -> bn1 -> a1(Q) -> GEMM2 split-K. P = pair tile, Q = 32KB a1 buffer. (T1 path)
__device__ __forceinline__ void gemm12(const char* P, char* Q,
                                       const bf16* __restrict__ W1T, const float* __restrict__ b1,
                                       const bf16* __restrict__ W2T,
                                       const float* __restrict__ scale1, const float* __restrict__ shift1,
                                       int w, int lane, f32x4 (&acc2)[4][4]) {
    #pragma unroll
    for (int m = 0; m < 4; ++m)
        #pragma unroll
        for (int n = 0; n < 4; ++n) acc2[m][n] = (f32x4){0.f, 0.f, 0.f, 0.f};

    #pragma unroll
    for (int half = 0; half < 2; ++half) {
        #pragma unroll
        for (int chunk = 0; chunk < 2; ++chunk) {
            int lcol = w * 64 + chunk * 32;
            int gbase = half * 256 + lcol;
            f32x4 acc1[4][2];
            gemm1_chunk(P, W1T, gbase, lane, acc1);
            #pragma unroll
            for (int n = 0; n < 2; ++n) {
                int lc = lcol + n * 16 + (lane & 15);
                int gc = half * 256 + lc;
                float bb = b1[gc], sc = scale1[gc], sh = shift1[gc];
                #pragma unroll
                for (int m = 0; m < 4; ++m)
                    #pragma unroll
                    for (int rr = 0; rr < 4; ++rr) {
                        int row = m * 16 + ((lane >> 4) << 2) + rr;
                        float a = fmaxf(fmaf(acc1[m][n][rr] + bb, sc, sh), 0.f);
                        *(bf16*)(Q + row * 512 + ((lc * 2) ^ ((row & 7) << 4))) = (bf16)a;
                    }
            }
        }
        __syncthreads();
        gemm2_half(Q, W2T, w, lane, half * 256, acc2);
        __syncthreads();
    }
}

// GEMM3..6 tail; expects a2 [64][256] bf16 swizzled at smem+0. Uses smem up to 32 KB.
__device__ __forceinline__ void mlp_tail(char* smem,
                                         const bf16* __restrict__ W3T, const float* __restrict__ b3,
                                         const bf16* __restrict__ W4T, const float* __restrict__ b4,
                                         const bf16* __restrict__ W5T, const float* __restrict__ b5,
                                         const float* __restrict__ W6, const float* __restrict__ b6,
                                         float* __restrict__ out, int E, int e0,
                                         int tid, int lane, int w) {
    // GEMM3: [64][256] @ [256][128]
    f32x4 acc3[4][2];
    #pragma unroll
    for (int m = 0; m < 4; ++m)
        #pragma unroll
        for (int n = 0; n < 2; ++n) acc3[m][n] = (f32x4){0.f, 0.f, 0.f, 0.f};
    for (int ks = 0; ks < 8; ++ks) {
        bf16x8 a[4];
        #pragma unroll
        for (int m = 0; m < 4; ++m) a[m] = lds_afrag(smem, 256, m * 16, ks * 32, lane);
        #pragma unroll
        for (int n = 0; n < 2; ++n) {
            bf16x8 b = glb_bfrag(W3T, 256, w * 32 + n * 16, ks * 32, lane);
            #pragma unroll
            for (int m = 0; m < 4; ++m) acc3[m][n] = MFMA16(a[m], b, acc3[m][n]);
        }
    }
    __syncthreads();
    if (tid < 32) ((float*)(smem + 24576))[tid] = W6[tid];  // a2 upper region dead now
    #pragma unroll
    for (int n = 0; n < 2; ++n) {
        int col = w * 32 + n * 16 + (lane & 15);
        float bb = b3[col];
        #pragma unroll
        for (int m = 0; m < 4; ++m)
            #pragma unroll
            for (int rr = 0; rr < 4; ++rr) {
                int row = m * 16 + ((lane >> 4) << 2) + rr;
                float a = fmaxf(acc3[m][n][rr] + bb, 0.f);
                *(bf16*)(smem + row * 256 + ((col * 2) ^ ((row & 7) << 4))) = (bf16)a;
            }
    }
    __syncthreads();

    // GEMM4: [64][128] @ [128][64]
    f32x4 acc4[4];
    #pragma unroll
    for (int m = 0; m < 4; ++m) acc4[m] = (f32x4){0.f, 0.f, 0.f, 0.f};
    for (int ks = 0; ks < 4; ++ks) {
        bf16x8 a[4];
        #pragma unroll
        for (int m = 0; m < 4; ++m) a[m] = lds_afrag(smem, 128, m * 16, ks * 32, lane);
        bf16x8 b = glb_bfrag(W4T, 128, w * 16, ks * 32, lane);
        #pragma unroll
        for (int m = 0; m < 4; ++m) acc4[m] = MFMA16(a[m], b, acc4[m]);
    }
    __syncthreads();
    {
        int col = w * 16 + (lane & 15);
        float bb = b4[col];
        #pragma unroll
        for (int m = 0; m < 4; ++m)
            #pragma unroll
            for (int rr = 0; rr < 4; ++rr) {
                int row = m * 16 + ((lane >> 4) << 2) + rr;
                float a = fmaxf(acc4[m][rr] + bb, 0.f);
                *(bf16*)(smem + row * 128 + ((col * 2) ^ ((row & 7) << 4))) = (bf16)a;
            }
    }
    __syncthreads();

    // GEMM5: [64][64] @ [64][32] -> a5 f32 at smem+16384 (waves 0,1)
    if (w < 2) {
        f32x4 acc5[4];
        #pragma unroll
        for (int m = 0; m < 4; ++m) acc5[m] = (f32x4){0.f, 0.f, 0.f, 0.f};
        for (int ks = 0; ks < 2; ++ks) {
            bf16x8 a[4];
            #pragma unroll
            for (int m = 0; m < 4; ++m) a[m] = lds_afrag(smem, 64, m * 16, ks * 32, lane);
            bf16x8 b = glb_bfrag(W5T, 64, w * 16, ks * 32, lane);
            #pragma unroll
            for (int m = 0; m < 4; ++m) acc5[m] = MFMA16(a[m], b, acc5[m]);
        }
        int col = w * 16 + (lane & 15);
        float bb = b5[col];
        float* a5f = (float*)(smem + 16384);
        #pragma unroll
        for (int m = 0; m < 4; ++m)
            #pragma unroll
            for (int rr = 0; rr < 4; ++rr) {
                int row = m * 16 + ((lane >> 4) << 2) + rr;
                a5f[row * 32 + col] = fmaxf(acc5[m][rr] + bb, 0.f);
            }
    }
    __syncthreads();

    if (tid < 64) {
        int ge = e0 + tid;
        if (ge < E) {
            const float* a5f = (const float*)(smem + 16384) + tid * 32;
            const float* w6 = (const float*)(smem + 24576);
            float s = b6[0];
            #pragma unroll
            for (int k = 0; k < 32; ++k) {
                int kk = (k + tid) & 31;
                s = fmaf(a5f[kk], w6[kk], s);
            }
            out[ge] = s;
        }
    }
}

// ---------------- tier-2 phase kernels (h1 + h2 materialized, zero recompute) ----------------

// A2: gather pair -> LDS, GEMM1 (chunked), h1 = acc + b1 -> bf16 store + stats1.
__global__ __launch_bounds__(256, 3)
void k_mlpA2(const bf16* __restrict__ xb2B, const int* __restrict__ ei, const float* __restrict__ ef,
             const bf16* __restrict__ W1T, const float* __restrict__ b1,
             float* __restrict__ sum1, float* __restrict__ sq1,
             bf16* __restrict__ h1G, int E) {
    __shared__ char smem[40960];
    const int tid = threadIdx.x, lane = tid & 63, w = tid >> 6;
    const int e0 = blockIdx.x * 64;
    const int* src = ei;
    const int* dst = ei + E;

    for (int it = tid; it < 64 * 40; it += 256) {
        int r = it / 40, c = it - r * 40;
        int ge = e0 + r;
        bf16x8 v;
        if (ge < E) {
            if (c < 16)      v = *(const bf16x8*)(xb2B + (size_t)src[ge] * 128 + c * 8);
            else if (c < 32) v = *(const bf16x8*)(xb2B + (size_t)dst[ge] * 128 + (c - 16) * 8);
            else {
                const float* p = ef + (size_t)ge * 64 + (c - 32) * 8;
                v = to_bf16x8(*(const float4*)p, *(const float4*)(p + 4));
            }
        } else {
            v = zero_bf16x8();
        }
        *(bf16x8*)(smem + r * 640 + ((c * 16) ^ ((r & 7) << 4))) = v;
    }
    __syncthreads();

    #pragma unroll
    for (int chunk = 0; chunk < 4; ++chunk) {
        int cbase = w * 128 + chunk * 32;
        f32x4 acc[4][2];
        gemm1_chunk(smem, W1T, cbase, lane, acc);
        #pragma unroll
        for (int n = 0; n < 2; ++n) {
            int col = cbase + n * 16 + (lane & 15);
            float bb = b1[col];
            float s = 0.f, q = 0.f;
            #pragma unroll
            for (int m = 0; m < 4; ++m)
                #pragma unroll
                for (int rr = 0; rr < 4; ++rr) {
                    int row = m * 16 + ((lane >> 4) << 2) + rr;
                    float h = acc[m][n][rr] + bb;
                    h1G[(size_t)(e0 + row) * 512 + col] = (bf16)h;
                    if (e0 + row < E) { s += h; q += h * h; }
                }
            s += __shfl_xor(s, 16); s += __shfl_xor(s, 32);
            q += __shfl_xor(q, 16); q += __shfl_xor(q, 32);
            if (lane < 16) { atomicAdd(&sum1[col], s); atomicAdd(&sq1[col], q); }
        }
    }
}

// B2: h1 -> bn1 during staging (2 halves, 32 KB LDS) -> GEMM2 -> h2 bf16 + stats2.
__global__ __launch_bounds__(256, 3)
void k_mlpB2(const bf16* __restrict__ h1G,
             const bf16* __restrict__ W2T, const float* __restrict__ b2,
             const float* __restrict__ scale1, const float* __restrict__ shift1,
             float* __restrict__ sum2, float* __restrict__ sq2,
             bf16* __restrict__ h2G, int E) {
    __shared__ char Q[32768];
    const int tid = threadIdx.x, lane = tid & 63, w = tid >> 6;
    const int e0 = blockIdx.x * 64;

    f32x4 acc2[4][4];
    #pragma unroll
    for (int m = 0; m < 4; ++m)
        #pragma unroll
        for (int n = 0; n < 4; ++n) acc2[m][n] = (f32x4){0.f, 0.f, 0.f, 0.f};

    #pragma unroll
    for (int half = 0; half < 2; ++half) {
        stage_bn_half(Q, h1G, 512, half * 256, scale1, shift1, e0, tid);
        __syncthreads();
        gemm2_half(Q, W2T, w, lane, half * 256, acc2);
        __syncthreads();
    }

    const int cb2 = w * 64;
    #pragma unroll
    for (int n = 0; n < 4; ++n) {
        int col = cb2 + n * 16 + (lane & 15);
        float bb = b2[col];
        float s = 0.f, q = 0.f;
        #pragma unroll
        for (int m = 0; m < 4; ++m)
            #pragma unroll
            for (int rr = 0; rr < 4; ++rr) {
                int row = m * 16 + ((lane >> 4) << 2) + rr;
                float h = acc2[m][n][rr] + bb;
                h2G[(size_t)(e0 + row) * 256 + col] = (bf16)h;
                if (e0 + row < E) { s += h; q += h * h; }
            }
        s += __shfl_xor(s, 16); s += __shfl_xor(s, 32);
        q += __shfl_xor(q, 16); q += __shfl_xor(q, 32);
        if (lane < 16) { atomicAdd(&sum2[col], s); atomicAdd(&sq2[col], q); }
    }
}

// C2: h2 -> bn2 during staging -> GEMM3..6 -> out.
__global__ __launch_bounds__(256, 4)
void k_mlpC2(const bf16* __restrict__ h2G,
             const bf16* __restrict__ W3T, const float* __restrict__ b3,
             const bf16* __restrict__ W4T, const float* __restrict__ b4,
             const bf16* __restrict__ W5T, const float* __restrict__ b5,
             const float* __restrict__ W6, const float* __restrict__ b6,
             const float* __restrict__ scale2, const float* __restrict__ shift2,
             float* __restrict__ out, int E) {
    __shared__ char Q[32768];
    const int tid = threadIdx.x, lane = tid & 63, w = tid >> 6;
    const int e0 = blockIdx.x * 64;

    stage_bn_half(Q, h2G, 256, 0, scale2, shift2, e0, tid);
    __syncthreads();

    mlp_tail(Q, W3T, b3, W4T, b4, W5T, b5, W6, b6, out, E, e0, tid, lane, w);
}

// ---------------- tier-1 phase kernels (pair recompute, proven R4) ----------------

__global__ __launch_bounds__(256, 3)
void k_mlpA(const bf16* __restrict__ xb2B, const int* __restrict__ ei, const float* __restrict__ ef,
            const bf16* __restrict__ W1T, const float* __restrict__ b1,
            float* __restrict__ sum1, float* __restrict__ sq1,
            bf16* __restrict__ pairG, int E) {
    __shared__ char smem[40960];
    const int tid = threadIdx.x, lane = tid & 63, w = tid >> 6;
    const int e0 = blockIdx.x * 64;
    const int* src = ei;
    const int* dst = ei + E;

    for (int it = tid; it < 64 * 40; it += 256) {
        int r = it / 40, c = it - r * 40;
        int ge = e0 + r;
        bf16x8 v;
        if (ge < E) {
            if (c < 16)      v = *(const bf16x8*)(xb2B + (size_t)src[ge] * 128 + c * 8);
            else if (c < 32) v = *(const bf16x8*)(xb2B + (size_t)dst[ge] * 128 + (c - 16) * 8);
            else {
                const float* p = ef + (size_t)ge * 64 + (c - 32) * 8;
                v = to_bf16x8(*(const float4*)p, *(const float4*)(p + 4));
            }
        } else {
            v = zero_bf16x8();
        }
        *(bf16x8*)(smem + r * 640 + ((c * 16) ^ ((r & 7) << 4))) = v;
        *(bf16x8*)(pairG + (size_t)ge * 320 + c * 8) = v;
    }
    __syncthreads();

    #pragma unroll
    for (int chunk = 0; chunk < 4; ++chunk) {
        int cbase = w * 128 + chunk * 32;
        f32x4 acc[4][2];
        gemm1_chunk(smem, W1T, cbase, lane, acc);
        #pragma unroll
        for (int n = 0; n < 2; ++n) {
            int col = cbase + n * 16 + (lane & 15);
            float bb = b1[col];
            float s = 0.f, q = 0.f;
            #pragma unroll
            for (int m = 0; m < 4; ++m)
                #pragma unroll
                for (int rr = 0; rr < 4; ++rr) {
                    int row = m * 16 + ((lane >> 4) << 2) + rr;
                    if (e0 + row < E) {
                        float h = acc[m][n][rr] + bb;
                        s += h; q += h * h;
                    }
                }
            s += __shfl_xor(s, 16); s += __shfl_xor(s, 32);
            q += __shfl_xor(q, 16); q += __shfl_xor(q, 32);
            if (lane < 16) { atomicAdd(&sum1[col], s); atomicAdd(&sq1[col], q); }
        }
    }
}

__global__ __launch_bounds__(256, 2)
void k_mlpB(const bf16* __restrict__ pairG,
            const bf16* __restrict__ W1T, const float* __restrict__ b1,
            const bf16* __restrict__ W2T, const float* __restrict__ b2,
            const float* __restrict__ scale1, const float* __restrict__ shift1,
            float* __restrict__ sum2, float* __restrict__ sq2, int E) {
    __shared__ char smem[40960 + 32768];
    char* P = smem;
    char* Q = smem + 40960;
    const int tid = threadIdx.x, lane = tid & 63, w = tid >> 6;
    const int e0 = blockIdx.x * 64;

    stage_pair_glb(P, pairG, e0, tid);
    __syncthreads();

    f32x4 acc2[4][4];
    gemm12(P, Q, W1T, b1, W2T, scale1, shift1, w, lane, acc2);

    const int cb2 = w * 64;
    #pragma unroll
    for (int n = 0; n < 4; ++n) {
        int col = cb2 + n * 16 + (lane & 15);
        float bb = b2[col];
        float s = 0.f, q = 0.f;
        #pragma unroll
        for (int m = 0; m < 4; ++m)
            #pragma unroll
            for (int rr = 0; rr < 4; ++rr) {
                int row = m * 16 + ((lane >> 4) << 2) + rr;
                if (e0 + row < E) {
                    float h = acc2[m][n][rr] + bb;
                    s += h; q += h * h;
                }
            }
        s += __shfl_xor(s, 16); s += __shfl_xor(s, 32);
        q += __shfl_xor(q, 16); q += __shfl_xor(q, 32);
        if (lane < 16) { atomicAdd(&sum2[col], s); atomicAdd(&sq2[col], q); }
    }
}

__global__ __launch_bounds__(256, 2)
void k_mlpC(const bf16* __restrict__ pairG,
            const bf16* __restrict__ W1T, const float* __restrict__ b1,
            const bf16* __restrict__ W2T, const float* __restrict__ b2,
            const bf16* __restrict__ W3T, const float* __restrict__ b3,
            const bf16* __restrict__ W4T, const float* __restrict__ b4,
            const bf16* __restrict__ W5T, const float* __restrict__ b5,
            const float* __restrict__ W6, const float* __restrict__ b6,
            const float* __restrict__ scale1, const float* __restrict__ shift1,
            const float* __restrict__ scale2, const float* __restrict__ shift2,
            float* __restrict__ out, int E) {
    __shared__ char smem[40960 + 32768];
    char* P = smem;
    char* Q = smem + 40960;
    const int tid = threadIdx.x, lane = tid & 63, w = tid >> 6;
    const int e0 = blockIdx.x * 64;

    stage_pair_glb(P, pairG, e0, tid);
    __syncthreads();

    f32x4 acc2[4][4];
    gemm12(P, Q, W1T, b1, W2T, scale1, shift1, w, lane, acc2);
    const int cb2 = w * 64;
    #pragma unroll
    for (int n = 0; n < 4; ++n) {
        int col = cb2 + n * 16 + (lane & 15);
        float bb = b2[col], sc = scale2[col], sh = shift2[col];
        #pragma unroll
        for (int m = 0; m < 4; ++m)
            #pragma unroll
            for (int rr = 0; rr < 4; ++rr) {
                int row = m * 16 + ((lane >> 4) << 2) + rr;
                float a = fmaxf(fmaf(acc2[m][n][rr] + bb, sc, sh), 0.f);
                *(bf16*)(Q + row * 512 + ((col * 2) ^ ((row & 7) << 4))) = (bf16)a;
            }
    }
    __syncthreads();

    mlp_tail(Q, W3T, b3, W4T, b4, W5T, b5, W6, b6, out, E, e0, tid, lane, w);
}

// ---------------- T0 fallback: fused edge MLP (3 gather passes, proven R1) ----------------
template <int PASS>
__global__ __launch_bounds__(256, 2)
void k_mlp(const float* __restrict__ x, const int* __restrict__ ei, const float* __restrict__ ef,
           const bf16* __restrict__ W1T, const float* __restrict__ b1,
           const bf16* __restrict__ W2T, const float* __restrict__ b2,
           const bf16* __restrict__ W3T, const float* __restrict__ b3,
           const bf16* __restrict__ W4T, const float* __restrict__ b4,
           const bf16* __restrict__ W5T, const float* __restrict__ b5,
           const float* __restrict__ W6, const float* __restrict__ b6,
           const float* __restrict__ scale1, const float* __restrict__ shift1,
           const float* __restrict__ scale2, const float* __restrict__ shift2,
           float* __restrict__ sum1, float* __restrict__ sq1,
           float* __restrict__ sum2, float* __restrict__ sq2,
           float* __restrict__ out, int E) {
    __shared__ char smem[65536];
    const int tid = threadIdx.x, lane = tid & 63, w = tid >> 6;
    const int e0 = blockIdx.x * 64;
    const int* src = ei;
    const int* dst = ei + E;

    for (int it = tid; it < 64 * 40; it += 256) {
        int r = it / 40, c = it - r * 40;
        int ge = e0 + r;
        float4 fa = {0, 0, 0, 0}, fb = {0, 0, 0, 0};
        if (ge < E) {
            int base = c * 8;
            const float* p;
            if (base < 128)      p = x + (size_t)src[ge] * 128 + base;
            else if (base < 256) p = x + (size_t)dst[ge] * 128 + (base - 128);
            else                 p = ef + (size_t)ge * 64 + (base - 256);
            fa = *(const float4*)p;
            fb = *(const float4*)(p + 4);
        }
        bf16x8 v = to_bf16x8(fa, fb);
        *(bf16x8*)(smem + r * 640 + ((c * 16) ^ ((r & 7) << 4))) = v;
    }
    __syncthreads();

    f32x4 acc[4][8];
    run_gemm1(smem, W1T, w, lane, acc);
    const int cb = w * 128;

    if (PASS == 0) {
        #pragma unroll
        for (int n = 0; n < 8; ++n) {
            int col = cb + n * 16 + (lane & 15);
            float bb = b1[col];
            float s = 0.f, q = 0.f;
            #pragma unroll
            for (int m = 0; m < 4; ++m)
                #pragma unroll
                for (int rr = 0; rr < 4; ++rr) {
                    int row = m * 16 + ((lane >> 4) << 2) + rr;
                    if (e0 + row < E) {
                        float h = acc[m][n][rr] + bb;
                        s += h; q += h * h;
                    }
                }
            s += __shfl_xor(s, 16); s += __shfl_xor(s, 32);
            q += __shfl_xor(q, 16); q += __shfl_xor(q, 32);
            if (lane < 16) { atomicAdd(&sum1[col], s); atomicAdd(&sq1[col], q); }
        }
        return;
    }

    __syncthreads();
    #pragma unroll
    for (int n = 0; n < 8; ++n) {
        int col = cb + n * 16 + (lane & 15);
        float bb = b1[col], sc = scale1[col], sh = shift1[col];
        #pragma unroll
        for (int m = 0; m < 4; ++m)
            #pragma unroll
            for (int rr = 0; rr < 4; ++rr) {
                int row = m * 16 + ((lane >> 4) << 2) + rr;
                float a = fmaxf(fmaf(acc[m][n][rr] + bb, sc, sh), 0.f);
                *(bf16*)(smem + row * 1024 + ((col * 2) ^ ((row & 7) << 4))) = (bf16)a;
            }
    }
    __syncthreads();

    f32x4 acc2[4][4];
    #pragma unroll
    for (int m = 0; m < 4; ++m)
        #pragma unroll
        for (int n = 0; n < 4; ++n) acc2[m][n] = (f32x4){0.f, 0.f, 0.f, 0.f};
    #pragma unroll 2
    for (int ks = 0; ks < 16; ++ks) {
        bf16x8 a[4];
        #pragma unroll
        for (int m = 0; m < 4; ++m) a[m] = lds_afrag(smem, 512, m * 16, ks * 32, lane);
        #pragma unroll
        for (int n = 0; n < 4; ++n) {
            bf16x8 b = glb_bfrag(W2T, 512, w * 64 + n * 16, ks * 32, lane);
            #pragma unroll
            for (int m = 0; m < 4; ++m) acc2[m][n] = MFMA16(a[m], b, acc2[m][n]);
        }
    }
    const int cb2 = w * 64;

    if (PASS == 1) {
        #pragma unroll
        for (int n = 0; n < 4; ++n) {
            int col = cb2 + n * 16 + (lane & 15);
            float bb = b2[col];
            float s = 0.f, q = 0.f;
            #pragma unroll
            for (int m = 0; m < 4; ++m)
                #pragma unroll
                for (int rr = 0; rr < 4; ++rr) {
                    int row = m * 16 + ((lane >> 4) << 2) + rr;
                    if (e0 + row < E) {
                        float h = acc2[m][n][rr] + bb;
                        s += h; q += h * h;
                    }
                }
            s += __shfl_xor(s, 16); s += __shfl_xor(s, 32);
            q += __shfl_xor(q, 16); q += __shfl_xor(q, 32);
            if (lane < 16) { atomicAdd(&sum2[col], s); atomicAdd(&sq2[col], q); }
        }
        return;
    }

    __syncthreads();
    if (tid < 32) *(float*)(smem + 49152 + tid * 4) = W6[tid];
    #pragma unroll
    for (int n = 0; n < 4; ++n) {
        int col = cb2 + n * 16 + (lane & 15);
        float bb = b2[col], sc = scale2[col], sh = shift2[col];
        #pragma unroll
        for (int m = 0; m < 4; ++m)
            #pragma unroll
            for (int rr = 0; rr < 4; ++rr) {
                int row = m * 16 + ((lane >> 4) << 2) + rr;
                float a = fmaxf(fmaf(acc2[m][n][rr] + bb, sc, sh), 0.f);
                *(bf16*)(smem + row * 512 + ((col * 2) ^ ((row & 7) << 4))) = (bf16)a;
            }
    }
    __syncthreads();

    f32x4 acc3[4][2];
    #pragma unroll
    for (int m = 0; m < 4; ++m)
        #pragma unroll
        for (int n = 0; n < 2; ++n) acc3[m][n] = (f32x4){0.f, 0.f, 0.f, 0.f};
    for (int ks = 0; ks < 8; ++ks) {
        bf16x8 a[4];
        #pragma unroll
        for (int m = 0; m < 4; ++m) a[m] = lds_afrag(smem, 256, m * 16, ks * 32, lane);
        #pragma unroll
        for (int n = 0; n < 2; ++n) {
            bf16x8 b = glb_bfrag(W3T, 256, w * 32 + n * 16, ks * 32, lane);
            #pragma unroll
            for (int m = 0; m < 4; ++m) acc3[m][n] = MFMA16(a[m], b, acc3[m][n]);
        }
    }
    __syncthreads();
    #pragma unroll
    for (int n = 0; n < 2; ++n) {
        int col = w * 32 + n * 16 + (lane & 15);
        float bb = b3[col];
        #pragma unroll
        for (int m = 0; m < 4; ++m)
            #pragma unroll
            for (int rr = 0; rr < 4; ++rr) {
                int row = m * 16 + ((lane >> 4) << 2) + rr;
                float a = fmaxf(acc3[m][n][rr] + bb, 0.f);
                *(bf16*)(smem + row * 256 + ((col * 2) ^ ((row & 7) << 4))) = (bf16)a;
            }
    }
    __syncthreads();

    f32x4 acc4[4];
    #pragma unroll
    for (int m = 0; m < 4; ++m) acc4[m] = (f32x4){0.f, 0.f, 0.f, 0.f};
    for (int ks = 0; ks < 4; ++ks) {
        bf16x8 a[4];
        #pragma unroll
        for (int m = 0; m < 4; ++m) a[m] = lds_afrag(smem, 128, m * 16, ks * 32, lane);
        bf16x8 b = glb_bfrag(W4T, 128, w * 16, ks * 32, lane);
        #pragma unroll
        for (int m = 0; m < 4; ++m) acc4[m] = MFMA16(a[m], b, acc4[m]);
    }
    __syncthreads();
    {
        int col = w * 16 + (lane & 15);
        float bb = b4[col];
        #pragma unroll
        for (int m = 0; m < 4; ++m)
            #pragma unroll
            for (int rr = 0; rr < 4; ++rr) {
                int row = m * 16 + ((lane >> 4) << 2) + rr;
                float a = fmaxf(acc4[m][rr] + bb, 0.f);
                *(bf16*)(smem + row * 128 + ((col * 2) ^ ((row & 7) << 4))) = (bf16)a;
            }
    }
    __syncthreads();

    if (w < 2) {
        f32x4 acc5[4];
        #pragma unroll
        for (int m = 0; m < 4; ++m) acc5[m] = (f32x4){0.f, 0.f, 0.f, 0.f};
        for (int ks = 0; ks < 2; ++ks) {
            bf16x8 a[4];
            #pragma unroll
            for (int m = 0; m < 4; ++m) a[m] = lds_afrag(smem, 64, m * 16, ks * 32, lane);
            bf16x8 b = glb_bfrag(W5T, 64, w * 16, ks * 32, lane);
            #pragma unroll
            for (int m = 0; m < 4; ++m) acc5[m] = MFMA16(a[m], b, acc5[m]);
        }
        int col = w * 16 + (lane & 15);
        float bb = b5[col];
        float* a5f = (float*)(smem + 16384);
        #pragma unroll
        for (int m = 0; m < 4; ++m)
            #pragma unroll
            for (int rr = 0; rr < 4; ++rr) {
                int row = m * 16 + ((lane >> 4) << 2) + rr;
                a5f[row * 32 + col] = fmaxf(acc5[m][rr] + bb, 0.f);
            }
    }
    __syncthreads();

    if (tid < 64) {
        int ge = e0 + tid;
        if (ge < E) {
            const float* a5f = (const float*)(smem + 16384) + tid * 32;
            const float* w6 = (const float*)(smem + 49152);
            float s = b6[0];
            #pragma unroll
            for (int k = 0; k < 32; ++k) {
                int kk = (k + tid) & 31;
                s = fmaf(a5f[kk], w6[kk], s);
            }
            out[ge] = s;
        }
    }
}

// ---------------- launch ----------------

extern "C" void kernel_launch(void* const* d_in, const int* in_sizes, int n_in,
                              void* d_out, int out_size, void* d_ws, size_t ws_size,
                              hipStream_t stream) {
    const float* x      = (const float*)d_in[0];
    const int*   ei     = (const int*)d_in[1];
    const float* ef     = (const float*)d_in[2];
    const float* W_nb   = (const float*)d_in[4];
    const float* b_nb   = (const float*)d_in[5];
    const float* W_self = (const float*)d_in[6];
    const float* b_self = (const float*)d_in[7];
    const float* W1 = (const float*)d_in[8];  const float* b1 = (const float*)d_in[9];
    const float* W2 = (const float*)d_in[10]; const float* b2 = (const float*)d_in[11];
    const float* W3 = (const float*)d_in[12]; const float* b3 = (const float*)d_in[13];
    const float* W4 = (const float*)d_in[14]; const float* b4 = (const float*)d_in[15];
    const float* W5 = (const float*)d_in[16]; const float* b5 = (const float*)d_in[17];
    const float* W6 = (const float*)d_in[18]; const float* b6 = (const float*)d_in[19];
    const float* g1 = (const float*)d_in[20]; const float* beta1 = (const float*)d_in[21];
    const float* g2 = (const float*)d_in[22]; const float* beta2 = (const float*)d_in[23];

    const int N = in_sizes[0] / 128;
    const int E = in_sizes[1] / 2;
    const int mlpGrid = (E + 63) / 64;
    const size_t Epad = (size_t)mlpGrid * 64;

    char* ws = (char*)d_ws;
    size_t off = 0;
    auto alloc = [&](size_t bytes) {
        size_t o = off;
        off = (off + bytes + 255) & ~(size_t)255;
        return o;
    };
    size_t oDeg = alloc((size_t)N * 4);
    size_t oCur = alloc((size_t)N * 4);
    size_t oSum1 = alloc(512 * 4), oSq1 = alloc(512 * 4);
    size_t oSum2 = alloc(256 * 4), oSq2 = alloc(256 * 4);
    size_t zeroEnd = off;
    size_t oOff = alloc((size_t)(N + 1) * 4);
    size_t oInv = alloc((size_t)N * 4);
    size_t oEid = alloc((size_t)E * 4);
    size_t oSm  = alloc((size_t)N * 192 * 4);
    size_t oXb1 = alloc((size_t)N * 128 * 4);
    size_t oXb2 = alloc((size_t)N * 128 * 4);
    size_t oXb2B = alloc((size_t)N * 128 * 2);
    size_t oScale1 = alloc(512 * 4), oShift1 = alloc(512 * 4);
    size_t oScale2 = alloc(256 * 4), oShift2 = alloc(256 * 4);
    size_t oWcat = alloc(128 * 320 * 2);
    size_t oW1T = alloc((size_t)512 * 320 * 2);
    size_t oW2T = alloc((size_t)256 * 512 * 2);
    size_t oW3T = alloc((size_t)128 * 256 * 2);
    size_t oW4T = alloc((size_t)64 * 128 * 2);
    size_t oW5T = alloc((size_t)32 * 64 * 2);
    size_t baseEnd = off;

    auto align256 = [](size_t v) { return (v + 255) & ~(size_t)255; };
    // tier-2 layout (h1 + h2, bf16)
    size_t oH1 = align256(baseEnd);
    size_t oH2 = align256(oH1 + Epad * 512 * 2);
    size_t m2End = align256(oH2 + Epad * 256 * 2);
    // tier-1 layout (pair), aliases the same region
    size_t oPair = align256(baseEnd);
    size_t m1End = align256(oPair + Epad * 320 * 2);

    int mode = (ws_size >= m2End) ? 2 : (ws_size >= m1End) ? 1 : (ws_size >= baseEnd) ? 0 : -1;
    if (mode < 0) return;

    float* deg = (float*)(ws + oDeg);
    unsigned* cursor = (unsigned*)(ws + oCur);
    float* sum1 = (float*)(ws + oSum1); float* sq1 = (float*)(ws + oSq1);
    float* sum2 = (float*)(ws + oSum2); float* sq2 = (float*)(ws + oSq2);
    unsigned* offsets = (unsigned*)(ws + oOff);
    float* invdeg = (float*)(ws + oInv);
    unsigned* eid = (unsigned*)(ws + oEid);
    float* sm  = (float*)(ws + oSm);
    float* xb1 = (float*)(ws + oXb1);
    float* xb2 = (float*)(ws + oXb2);
    bf16* xb2B = (bf16*)(ws + oXb2B);
    float* scale1 = (float*)(ws + oScale1); float* shift1 = (float*)(ws + oShift1);
    float* scale2 = (float*)(ws + oScale2); float* shift2 = (float*)(ws + oShift2);
    bf16* WcatT = (bf16*)(ws + oWcat);
    bf16* W1T = (bf16*)(ws + oW1T);
    bf16* W2T = (bf16*)(ws + oW2T);
    bf16* W3T = (bf16*)(ws + oW3T);
    bf16* W4T = (bf16*)(ws + oW4T);
    bf16* W5T = (bf16*)(ws + oW5T);
    bf16* h1G = (bf16*)(ws + oH1);
    bf16* h2G = (bf16*)(ws + oH2);
    bf16* pairG = (bf16*)(ws + oPair);

    hipMemsetAsync(ws, 0, zeroEnd, stream);

    k_transpose<<<(128 * 128 + 255) / 256, 256, 0, stream>>>(W_self, WcatT, 128, 128, 320, 0);
    k_transpose<<<(192 * 128 + 255) / 256, 256, 0, stream>>>(W_nb, WcatT, 192, 128, 320, 128);
    k_transpose<<<(320 * 512 + 255) / 256, 256, 0, stream>>>(W1, W1T, 320, 512, 320, 0);
    k_transpose<<<(512 * 256 + 255) / 256, 256, 0, stream>>>(W2, W2T, 512, 256, 512, 0);
    k_transpose<<<(256 * 128 + 255) / 256, 256, 0, stream>>>(W3, W3T, 256, 128, 256, 0);
    k_transpose<<<(128 * 64 + 255) / 256, 256, 0, stream>>>(W4, W4T, 128, 64, 128, 0);
    k_transpose<<<(64 * 32 + 255) / 256, 256, 0, stream>>>(W5, W5T, 64, 32, 64, 0);

    const int* dst = ei + E;
    k_deg<<<(E + 255) / 256, 256, 0, stream>>>(dst, deg, E);
    k_scan<<<1, 1024, 0, stream>>>(deg, offsets, invdeg, N);
    k_scatter<<<(E + 255) / 256, 256, 0, stream>>>(dst, offsets, cursor, eid, E);

    k_agg<<<(N + 15) / 16, 256, 0, stream>>>(x, ef, ei, offsets, invdeg, eid, sm, N);
    k_nodegemm<0><<<(N + 63) / 64, 256, 0, stream>>>(x, sm, WcatT, b_self, b_nb, offsets, xb1, nullptr, N);
    k_agg<<<(N + 15) / 16, 256, 0, stream>>>(xb1, ef, ei, offsets, invdeg, eid, sm, N);

    const float invE = 1.0f / (float)E;
    if (mode == 2) {
        k_nodegemm<1><<<(N + 63) / 64, 256, 0, stream>>>(xb1, sm, WcatT, b_self, b_nb, offsets, nullptr, xb2B, N);
        k_mlpA2<<<mlpGrid, 256, 0, stream>>>(xb2B, ei, ef, W1T, b1, sum1, sq1, h1G, E);
        k_finalize<<<2, 256, 0, stream>>>(sum1, sq1, g1, beta1, scale1, shift1, 512, invE);
        k_mlpB2<<<mlpGrid, 256, 0, stream>>>(h1G, W2T, b2, scale1, shift1, sum2, sq2, h2G, E);
        k_finalize<<<1, 256, 0, stream>>>(sum2, sq2, g2, beta2, scale2, shift2, 256, invE);
        k_mlpC2<<<mlpGrid, 256, 0, stream>>>(h2G, W3T, b3, W4T, b4, W5T, b5, W6, b6,
                                             scale2, shift2, (float*)d_out, E);
    } else if (mode == 1) {
        k_nodegemm<1><<<(N + 63) / 64, 256, 0, stream>>>(xb1, sm, WcatT, b_self, b_nb, offsets, nullptr, xb2B, N);
        k_mlpA<<<mlpGrid, 256, 0, stream>>>(xb2B, ei, ef, W1T, b1, sum1, sq1, pairG, E);
        k_finalize<<<2, 256, 0, stream>>>(sum1, sq1, g1, beta1, scale1, shift1, 512, invE);
        k_mlpB<<<mlpGrid, 256, 0, stream>>>(pairG, W1T, b1, W2T, b2, scale1, shift1, sum2, sq2, E);
        k_finalize<<<1, 256, 0, stream>>>(sum2, sq2, g2, beta2, scale2, shift2, 256, invE);
        k_mlpC<<<mlpGrid, 256, 0, stream>>>(pairG, W1T, b1, W2T, b2, W3T, b3, W4T, b4,
                                            W5T, b5, W6, b6, scale1, shift1,
                                            scale2, shift2, (float*)d_out, E);
    } else {
        k_nodegemm<0><<<(N + 63) / 64, 256, 0, stream>>>(xb1, sm, WcatT, b_self, b_nb, offsets, xb2, nullptr, N);
        k_mlp<0><<<mlpGrid, 256, 0, stream>>>(xb2, ei, ef, W1T, b1, W2T, b2, W3T, b3, W4T, b4,
                                              W5T, b5, W6, b6, scale1, shift1, scale2, shift2,
                                              sum1, sq1, sum2, sq2, (float*)d_out, E);
        k_finalize<<<2, 256, 0, stream>>>(sum1, sq1, g1, beta1, scale1, shift1, 512, invE);
        k_mlp<1><<<mlpGrid, 256, 0, stream>>>(xb2, ei, ef, W1T, b1, W2T, b2, W3T, b3, W4T, b4,
                                              W5T, b5, W6, b6, scale1, shift1, scale2, shift2,
                                              sum1, sq1, sum2, sq2, (float*)d_out, E);
        k_finalize<<<1, 256, 0, stream>>>(sum2, sq2, g2, beta2, scale2, shift2, 256, invE);
        k_mlp<2><<<mlpGrid, 256, 0, stream>>>(xb2, ei, ef, W1T, b1, W2T, b2, W3T, b3, W4T, b4,
                                              W5T, b5, W6, b6, scale1, shift1, scale2, shift2,
                                              sum1, sq1, sum2, sq2, (float*)d_out, E);
    }
}

// Round 8
// 2379.867 us; speedup vs baseline: 2.5388x; 1.3502x over previous
//
#include <hip/hip_runtime.h>

using bf16 = __bf16;
typedef bf16 bf16x8 __attribute__((ext_vector_type(8)));
typedef float f32x4 __attribute__((ext_vector_type(4)));

#define MFMA16(a, b, c) __builtin_amdgcn_mfma_f32_16x16x32_bf16(a, b, c, 0, 0, 0)

// ---------------- helpers ----------------

__device__ __forceinline__ bf16x8 to_bf16x8(float4 a, float4 b) {
    bf16x8 v;
    v[0] = (bf16)a.x; v[1] = (bf16)a.y; v[2] = (bf16)a.z; v[3] = (bf16)a.w;
    v[4] = (bf16)b.x; v[5] = (bf16)b.y; v[6] = (bf16)b.z; v[7] = (bf16)b.w;
    return v;
}

__device__ __forceinline__ bf16x8 zero_bf16x8() {
    bf16 z = (bf16)0.f;
    bf16x8 v = {z, z, z, z, z, z, z, z};
    return v;
}

// A-fragment from a swizzled row-major LDS tile [rows][ldK] bf16.
__device__ __forceinline__ bf16x8 lds_afrag(const char* smem, int ldK, int mbase, int kbase, int lane) {
    int r = mbase + (lane & 15);
    int off = (kbase + ((lane >> 4) << 3)) << 1;
    off ^= (r & 7) << 4;
    return *(const bf16x8*)(smem + r * (ldK << 1) + off);
}

__device__ __forceinline__ bf16x8 glb_bfrag(const bf16* __restrict__ WT, int K, int nbase, int kbase, int lane) {
    int n = nbase + (lane & 15);
    int k = kbase + ((lane >> 4) << 3);
    return *(const bf16x8*)(WT + (size_t)n * K + k);
}

// ---------------- small kernels ----------------

__global__ void k_transpose(const float* __restrict__ W, bf16* __restrict__ WT,
                            int K, int N, int ldT, int k0) {
    int idx = blockIdx.x * 256 + threadIdx.x;
    if (idx < K * N) {
        int k = idx / N, n = idx - k * N;
        WT[(size_t)n * ldT + k0 + k] = (bf16)W[idx];
    }
}

__global__ void k_deg(const int* __restrict__ dst, float* __restrict__ deg, int E) {
    int e = blockIdx.x * 256 + threadIdx.x;
    if (e < E) atomicAdd(&deg[dst[e]], 1.0f);
}

__global__ void k_scan(const float* __restrict__ deg, unsigned* __restrict__ offsets,
                       float* __restrict__ invdeg, int N) {
    __shared__ unsigned wsum[16];
    __shared__ unsigned carry_s, tot_s;
    const int tid = threadIdx.x, lane = tid & 63, wid = tid >> 6;
    if (tid == 0) carry_s = 0;
    __syncthreads();
    for (int base = 0; base < N; base += 1024) {
        int i = base + tid;
        unsigned v = (i < N) ? (unsigned)deg[i] : 0u;
        unsigned inc = v;
        #pragma unroll
        for (int d = 1; d < 64; d <<= 1) {
            unsigned t = (unsigned)__shfl_up((int)inc, d, 64);
            if (lane >= d) inc += t;
        }
        if (lane == 63) wsum[wid] = inc;
        __syncthreads();
        if (wid == 0) {
            unsigned wv = (lane < 16) ? wsum[lane] : 0u;
            unsigned winc = wv;
            #pragma unroll
            for (int d = 1; d < 16; d <<= 1) {
                unsigned t = (unsigned)__shfl_up((int)winc, d, 16);
                if ((lane & 15) >= d) winc += t;
            }
            if (lane < 16) wsum[lane] = winc - wv;
            if (lane == 15) tot_s = winc;
        }
        __syncthreads();
        if (i < N) {
            offsets[i] = carry_s + wsum[wid] + (inc - v);
            invdeg[i] = 1.0f / fmaxf(deg[i], 1.0f);
        }
        __syncthreads();
        if (tid == 0) carry_s += tot_s;
        __syncthreads();
    }
    if (tid == 0) offsets[N] = carry_s;
}

__global__ void k_scatter(const int* __restrict__ dst, const unsigned* __restrict__ offsets,
                          unsigned* __restrict__ cursor, unsigned* __restrict__ eid, int E) {
    int e = blockIdx.x * 256 + threadIdx.x;
    if (e < E) {
        int d = dst[e];
        unsigned p = atomicAdd(&cursor[d], 1u);
        eid[offsets[d] + p] = (unsigned)e;
    }
}

__global__ __launch_bounds__(256)
void k_agg(const float* __restrict__ xin, const float* __restrict__ ef, const int* __restrict__ src,
           const unsigned* __restrict__ offsets, const float* __restrict__ invdeg,
           const unsigned* __restrict__ eid, float* __restrict__ sm, int N) {
    const int lane = threadIdx.x & 63, w = threadIdx.x >> 6;
    int nb = blockIdx.x * 16 + w * 4;
    for (int j = 0; j < 4; ++j) {
        int n = nb + j;
        if (n >= N) return;
        unsigned o0 = offsets[n], o1 = offsets[n + 1];
        float s0 = 0.f, s1 = 0.f, s2 = 0.f;
        for (unsigned t = o0; t < o1; ++t) {
            int e = (int)eid[t];
            int v = src[e];
            s0 += xin[(size_t)v * 128 + lane];
            s1 += xin[(size_t)v * 128 + 64 + lane];
            s2 += ef[(size_t)e * 64 + lane];
        }
        float g = invdeg[n];
        sm[(size_t)n * 192 + lane] = s0 * g;
        sm[(size_t)n * 192 + 64 + lane] = s1 * g;
        sm[(size_t)n * 192 + 128 + lane] = s2 * g;
    }
}

template <int BF16OUT>
__global__ __launch_bounds__(256)
void k_nodegemm(const float* __restrict__ xin, const float* __restrict__ sm,
                const bf16* __restrict__ WcatT,
                const float* __restrict__ b_self, const float* __restrict__ b_nb,
                const unsigned* __restrict__ offsets,
                float* __restrict__ xout, bf16* __restrict__ xoutB, int N) {
    __shared__ char smem[64 * 320 * 2];
    const int tid = threadIdx.x, lane = tid & 63, w = tid >> 6;
    const int n0 = blockIdx.x * 64;
    for (int it = tid; it < 64 * 40; it += 256) {
        int r = it / 40, c = it - r * 40;
        int node = n0 + r;
        float4 fa = {0, 0, 0, 0}, fb = {0, 0, 0, 0};
        if (node < N) {
            int base = c * 8;
            const float* p = (base < 128) ? xin + (size_t)node * 128 + base
                                          : sm + (size_t)node * 192 + (base - 128);
            fa = *(const float4*)p;
            fb = *(const float4*)(p + 4);
        }
        bf16x8 v = to_bf16x8(fa, fb);
        *(bf16x8*)(smem + r * 640 + ((c * 16) ^ ((r & 7) << 4))) = v;
    }
    __syncthreads();

    f32x4 acc[4][2];
    #pragma unroll
    for (int m = 0; m < 4; ++m)
        #pragma unroll
        for (int n = 0; n < 2; ++n) acc[m][n] = (f32x4){0.f, 0.f, 0.f, 0.f};

    for (int ks = 0; ks < 10; ++ks) {
        bf16x8 a[4];
        #pragma unroll
        for (int m = 0; m < 4; ++m) a[m] = lds_afrag(smem, 320, m * 16, ks * 32, lane);
        #pragma unroll
        for (int n = 0; n < 2; ++n) {
            bf16x8 b = glb_bfrag(WcatT, 320, w * 32 + n * 16, ks * 32, lane);
            #pragma unroll
            for (int m = 0; m < 4; ++m) acc[m][n] = MFMA16(a[m], b, acc[m][n]);
        }
    }

    #pragma unroll
    for (int n = 0; n < 2; ++n) {
        int col = w * 32 + n * 16 + (lane & 15);
        float bs = b_self[col], bn = b_nb[col];
        #pragma unroll
        for (int m = 0; m < 4; ++m)
            #pragma unroll
            for (int rr = 0; rr < 4; ++rr) {
                int row = m * 16 + ((lane >> 4) << 2) + rr;
                int node = n0 + row;
                if (node < N) {
                    bool hd = offsets[node + 1] > offsets[node];
                    float val = fmaxf(acc[m][n][rr] + bs + (hd ? bn : 0.f), 0.f);
                    if (BF16OUT) xoutB[(size_t)node * 128 + col] = (bf16)val;
                    else         xout[(size_t)node * 128 + col] = val;
                }
            }
    }
}

__global__ void k_finalize(const float* __restrict__ sum, const float* __restrict__ sq,
                           const float* __restrict__ g, const float* __restrict__ beta,
                           float* __restrict__ scale, float* __restrict__ shift,
                           int n, float invE) {
    int i = blockIdx.x * 256 + threadIdx.x;
    if (i < n) {
        float m = sum[i] * invE;
        float v = sq[i] * invE - m * m;
        float sc = g[i] * rsqrtf(v + 1e-5f);
        scale[i] = sc;
        shift[i] = beta[i] - m * sc;
    }
}

// ---------------- shared MLP building blocks ----------------

__device__ __forceinline__ void gemm1_chunk(const char* P, const bf16* __restrict__ W1T,
                                            int cbase, int lane, f32x4 (&acc)[4][2]) {
    #pragma unroll
    for (int m = 0; m < 4; ++m)
        #pragma unroll
        for (int n = 0; n < 2; ++n) acc[m][n] = (f32x4){0.f, 0.f, 0.f, 0.f};
    for (int ks = 0; ks < 10; ++ks) {
        bf16x8 a[4];
        #pragma unroll
        for (int m = 0; m < 4; ++m) a[m] = lds_afrag(P, 320, m * 16, ks * 32, lane);
        #pragma unroll
        for (int n = 0; n < 2; ++n) {
            bf16x8 b = glb_bfrag(W1T, 320, cbase + n * 16, ks * 32, lane);
            #pragma unroll
            for (int m = 0; m < 4; ++m) acc[m][n] = MFMA16(a[m], b, acc[m][n]);
        }
    }
}

__device__ __forceinline__ void run_gemm1(const char* smem, const bf16* __restrict__ W1T,
                                          int w, int lane, f32x4 (&acc)[4][8]) {
    #pragma unroll
    for (int m = 0; m < 4; ++m)
        #pragma unroll
        for (int n = 0; n < 8; ++n) acc[m][n] = (f32x4){0.f, 0.f, 0.f, 0.f};
    #pragma unroll 2
    for (int ks = 0; ks < 10; ++ks) {
        bf16x8 a[4];
        #pragma unroll
        for (int m = 0; m < 4; ++m) a[m] = lds_afrag(smem, 320, m * 16, ks * 32, lane);
        #pragma unroll
        for (int n = 0; n < 8; ++n) {
            bf16x8 b = glb_bfrag(W1T, 320, w * 128 + n * 16, ks * 32, lane);
            #pragma unroll
            for (int m = 0; m < 4; ++m) acc[m][n] = MFMA16(a[m], b, acc[m][n]);
        }
    }
}

// gather pair tile (bf16 node features + f32 ef) into swizzled LDS P; optionally store to pairG
template <int STORE_PAIR>
__device__ __forceinline__ void stage_gather(char* P, const bf16* __restrict__ xb2B,
                                             const int* __restrict__ src, const int* __restrict__ dst,
                                             const float* __restrict__ ef, bf16* __restrict__ pairG,
                                             int e0, int E, int tid) {
    for (int it = tid; it < 64 * 40; it += 256) {
        int r = it / 40, c = it - r * 40;
        int ge = e0 + r;
        bf16x8 v;
        if (ge < E) {
            if (c < 16)      v = *(const bf16x8*)(xb2B + (size_t)src[ge] * 128 + c * 8);
            else if (c < 32) v = *(const bf16x8*)(xb2B + (size_t)dst[ge] * 128 + (c - 16) * 8);
            else {
                const float* p = ef + (size_t)ge * 64 + (c - 32) * 8;
                v = to_bf16x8(*(const float4*)p, *(const float4*)(p + 4));
            }
        } else {
            v = zero_bf16x8();
        }
        *(bf16x8*)(P + r * 640 + ((c * 16) ^ ((r & 7) << 4))) = v;
        if (STORE_PAIR) *(bf16x8*)(pairG + (size_t)ge * 320 + c * 8) = v;
    }
}

__device__ __forceinline__ void stage_pair_glb(char* P, const bf16* __restrict__ pairG,
                                               int e0, int tid) {
    for (int it = tid; it < 64 * 40; it += 256) {
        int r = it / 40, c = it - r * 40;
        bf16x8 v = *(const bf16x8*)(pairG + (size_t)(e0 + r) * 320 + c * 8);
        *(bf16x8*)(P + r * 640 + ((c * 16) ^ ((r & 7) << 4))) = v;
    }
}

__device__ __forceinline__ void gemm2_half(const char* a1buf, const bf16* __restrict__ W2T,
                                           int w, int lane, int kg0, f32x4 (&acc2)[4][4]) {
    #pragma unroll 2
    for (int ks = 0; ks < 8; ++ks) {
        bf16x8 a[4];
        #pragma unroll
        for (int m = 0; m < 4; ++m) a[m] = lds_afrag(a1buf, 256, m * 16, ks * 32, lane);
        #pragma unroll
        for (int n = 0; n < 4; ++n) {
            bf16x8 b = glb_bfrag(W2T, 512, w * 64 + n * 16, kg0 + ks * 32, lane);
            #pragma unroll
            for (int m = 0; m < 4; ++m) acc2[m][n] = MFMA16(a[m], b, acc2[m][n]);
        }
    }
}

// stage a [64][256] bf16 tile from hG applying bn+relu, swizzled into Q.
__device__ __forceinline__ void stage_bn_half(char* Q, const bf16* __restrict__ hG, int ldH,
                                              int hbase, const float* __restrict__ scale,
                                              const float* __restrict__ shift,
                                              int e0, int tid) {
    for (int it = tid; it < 64 * 32; it += 256) {
        int r = it >> 5, c = it & 31;
        int col0 = hbase + c * 8;
        bf16x8 v = *(const bf16x8*)(hG + (size_t)(e0 + r) * ldH + col0);
        float4 s0 = *(const float4*)(scale + col0);
        float4 s1 = *(const float4*)(scale + col0 + 4);
        float4 h0 = *(const float4*)(shift + col0);
        float4 h1 = *(const float4*)(shift + col0 + 4);
        bf16x8 o;
        o[0] = (bf16)fmaxf(fmaf((float)v[0], s0.x, h0.x), 0.f);
        o[1] = (bf16)fmaxf(fmaf((float)v[1], s0.y, h0.y), 0.f);
        o[2] = (bf16)fmaxf(fmaf((float)v[2], s0.z, h0.z), 0.f);
        o[3] = (bf16)fmaxf(fmaf((float)v[3], s0.w, h0.w), 0.f);
        o[4] = (bf16)fmaxf(fmaf((float)v[4], s1.x, h1.x), 0.f);
        o[5] = (bf16)fmaxf(fmaf((float)v[5], s1.y, h1.y), 0.f);
        o[6] = (bf16)fmaxf(fmaf((float)v[6], s1.z, h1.z), 0.f);
        o[7] = (bf16)fmaxf(fmaf((float)v[7], s1.w, h1.w), 0.f);
        *(bf16x8*)(Q + r * 512 + ((c * 16) ^ ((r & 7) << 4))) = o;
    }
}

// GEMM1(chunked) -> bn1 -> a1(Q) -> GEMM2 split-K.
__device__ __forceinline__ void gemm12(const char* P, char* Q,
                                       const bf16* __restrict__ W1T, const float* __restrict__ b1,
                                       const bf16* __restrict__ W2T,
                                       const float* __restrict__ scale1, const float* __restrict__ shift1,
                                       int w, int lane, f32x4 (&acc2)[4][4]) {
    #pragma unroll
    for (int m = 0; m < 4; ++m)
        #pragma unroll
        for (int n = 0; n < 4; ++n) acc2[m][n] = (f32x4){0.f, 0.f, 0.f, 0.f};

    #pragma unroll
    for (int half = 0; half < 2; ++half) {
        #pragma unroll
        for (int chunk = 0; chunk < 2; ++chunk) {
            int lcol = w * 64 + chunk * 32;
            int gbase = half * 256 + lcol;
            f32x4 acc1[4][2];
            gemm1_chunk(P, W1T, gbase, lane, acc1);
            #pragma unroll
            for (int n = 0; n < 2; ++n) {
                int lc = lcol + n * 16 + (lane & 15);
                int gc = half * 256 + lc;
                float bb = b1[gc], sc = scale1[gc], sh = shift1[gc];
                #pragma unroll
                for (int m = 0; m < 4; ++m)
                    #pragma unroll
                    for (int rr = 0; rr < 4; ++rr) {
                        int row = m * 16 + ((lane >> 4) << 2) + rr;
                        float a = fmaxf(fmaf(acc1[m][n][rr] + bb, sc, sh), 0.f);
                        *(bf16*)(Q + row * 512 + ((lc * 2) ^ ((row & 7) << 4))) = (bf16)a;
                    }
            }
        }
        __syncthreads();
        gemm2_half(Q, W2T, w, lane, half * 256, acc2);
        __syncthreads();
    }
}

// GEMM3..6 tail; expects a2 [64][256] bf16 swizzled at smem+0.
__device__ __forceinline__ void mlp_tail(char* smem,
                                         const bf16* __restrict__ W3T, const float* __restrict__ b3,
                                         const bf16* __restrict__ W4T, const float* __restrict__ b4,
                                         const bf16* __restrict__ W5T, const float* __restrict__ b5,
                                         const float* __restrict__ W6, const float* __restrict__ b6,
                                         float* __restrict__ out, int E, int e0,
                                         int tid, int lane, int w) {
    f32x4 acc3[4][2];
    #pragma unroll
    for (int m = 0; m < 4; ++m)
        #pragma unroll
        for (int n = 0; n < 2; ++n) acc3[m][n] = (f32x4){0.f, 0.f, 0.f, 0.f};
    for (int ks = 0; ks < 8; ++ks) {
        bf16x8 a[4];
        #pragma unroll
        for (int m = 0; m < 4; ++m) a[m] = lds_afrag(smem, 256, m * 16, ks * 32, lane);
        #pragma unroll
        for (int n = 0; n < 2; ++n) {
            bf16x8 b = glb_bfrag(W3T, 256, w * 32 + n * 16, ks * 32, lane);
            #pragma unroll
            for (int m = 0; m < 4; ++m) acc3[m][n] = MFMA16(a[m], b, acc3[m][n]);
        }
    }
    __syncthreads();
    if (tid < 32) ((float*)(smem + 24576))[tid] = W6[tid];
    #pragma unroll
    for (int n = 0; n < 2; ++n) {
        int col = w * 32 + n * 16 + (lane & 15);
        float bb = b3[col];
        #pragma unroll
        for (int m = 0; m < 4; ++m)
            #pragma unroll
            for (int rr = 0; rr < 4; ++rr) {
                int row = m * 16 + ((lane >> 4) << 2) + rr;
                float a = fmaxf(acc3[m][n][rr] + bb, 0.f);
                *(bf16*)(smem + row * 256 + ((col * 2) ^ ((row & 7) << 4))) = (bf16)a;
            }
    }
    __syncthreads();

    f32x4 acc4[4];
    #pragma unroll
    for (int m = 0; m < 4; ++m) acc4[m] = (f32x4){0.f, 0.f, 0.f, 0.f};
    for (int ks = 0; ks < 4; ++ks) {
        bf16x8 a[4];
        #pragma unroll
        for (int m = 0; m < 4; ++m) a[m] = lds_afrag(smem, 128, m * 16, ks * 32, lane);
        bf16x8 b = glb_bfrag(W4T, 128, w * 16, ks * 32, lane);
        #pragma unroll
        for (int m = 0; m < 4; ++m) acc4[m] = MFMA16(a[m], b, acc4[m]);
    }
    __syncthreads();
    {
        int col = w * 16 + (lane & 15);
        float bb = b4[col];
        #pragma unroll
        for (int m = 0; m < 4; ++m)
            #pragma unroll
            for (int rr = 0; rr < 4; ++rr) {
                int row = m * 16 + ((lane >> 4) << 2) + rr;
                float a = fmaxf(acc4[m][rr] + bb, 0.f);
                *(bf16*)(smem + row * 128 + ((col * 2) ^ ((row & 7) << 4))) = (bf16)a;
            }
    }
    __syncthreads();

    if (w < 2) {
        f32x4 acc5[4];
        #pragma unroll
        for (int m = 0; m < 4; ++m) acc5[m] = (f32x4){0.f, 0.f, 0.f, 0.f};
        for (int ks = 0; ks < 2; ++ks) {
            bf16x8 a[4];
            #pragma unroll
            for (int m = 0; m < 4; ++m) a[m] = lds_afrag(smem, 64, m * 16, ks * 32, lane);
            bf16x8 b = glb_bfrag(W5T, 64, w * 16, ks * 32, lane);
            #pragma unroll
            for (int m = 0; m < 4; ++m) acc5[m] = MFMA16(a[m], b, acc5[m]);
        }
        int col = w * 16 + (lane & 15);
        float bb = b5[col];
        float* a5f = (float*)(smem + 16384);
        #pragma unroll
        for (int m = 0; m < 4; ++m)
            #pragma unroll
            for (int rr = 0; rr < 4; ++rr) {
                int row = m * 16 + ((lane >> 4) << 2) + rr;
                a5f[row * 32 + col] = fmaxf(acc5[m][rr] + bb, 0.f);
            }
    }
    __syncthreads();

    if (tid < 64) {
        int ge = e0 + tid;
        if (ge < E) {
            const float* a5f = (const float*)(smem + 16384) + tid * 32;
            const float* w6 = (const float*)(smem + 24576);
            float s = b6[0];
            #pragma unroll
            for (int k = 0; k < 32; ++k) {
                int kk = (k + tid) & 31;
                s = fmaf(a5f[kk], w6[kk], s);
            }
            out[ge] = s;
        }
    }
}

// ---------------- MLP phase kernels ----------------

// A (tiers 1/2): gather -> GEMM1 chunked -> stats1 [+ pair store]
template <int STORE_PAIR>
__global__ __launch_bounds__(256, 3)
void k_mlpA(const bf16* __restrict__ xb2B, const int* __restrict__ ei, const float* __restrict__ ef,
            const bf16* __restrict__ W1T, const float* __restrict__ b1,
            float* __restrict__ sum1, float* __restrict__ sq1,
            bf16* __restrict__ pairG, int E) {
    __shared__ char smem[40960];
    const int tid = threadIdx.x, lane = tid & 63, w = tid >> 6;
    const int e0 = blockIdx.x * 64;
    stage_gather<STORE_PAIR>(smem, xb2B, ei, ei + E, ef, pairG, e0, E, tid);
    __syncthreads();

    #pragma unroll
    for (int chunk = 0; chunk < 4; ++chunk) {
        int cbase = w * 128 + chunk * 32;
        f32x4 acc[4][2];
        gemm1_chunk(smem, W1T, cbase, lane, acc);
        #pragma unroll
        for (int n = 0; n < 2; ++n) {
            int col = cbase + n * 16 + (lane & 15);
            float bb = b1[col];
            float s = 0.f, q = 0.f;
            #pragma unroll
            for (int m = 0; m < 4; ++m)
                #pragma unroll
                for (int rr = 0; rr < 4; ++rr) {
                    int row = m * 16 + ((lane >> 4) << 2) + rr;
                    if (e0 + row < E) {
                        float h = acc[m][n][rr] + bb;
                        s += h; q += h * h;
                    }
                }
            s += __shfl_xor(s, 16); s += __shfl_xor(s, 32);
            q += __shfl_xor(q, 16); q += __shfl_xor(q, 32);
            if (lane < 16) { atomicAdd(&sum1[col], s); atomicAdd(&sq1[col], q); }
        }
    }
}

// A (tier 3): gather -> GEMM1 chunked -> h1 bf16 store + stats1
__global__ __launch_bounds__(256, 3)
void k_mlpA2(const bf16* __restrict__ xb2B, const int* __restrict__ ei, const float* __restrict__ ef,
             const bf16* __restrict__ W1T, const float* __restrict__ b1,
             float* __restrict__ sum1, float* __restrict__ sq1,
             bf16* __restrict__ h1G, int E) {
    __shared__ char smem[40960];
    const int tid = threadIdx.x, lane = tid & 63, w = tid >> 6;
    const int e0 = blockIdx.x * 64;
    stage_gather<0>(smem, xb2B, ei, ei + E, ef, nullptr, e0, E, tid);
    __syncthreads();

    #pragma unroll
    for (int chunk = 0; chunk < 4; ++chunk) {
        int cbase = w * 128 + chunk * 32;
        f32x4 acc[4][2];
        gemm1_chunk(smem, W1T, cbase, lane, acc);
        #pragma unroll
        for (int n = 0; n < 2; ++n) {
            int col = cbase + n * 16 + (lane & 15);
            float bb = b1[col];
            float s = 0.f, q = 0.f;
            #pragma unroll
            for (int m = 0; m < 4; ++m)
                #pragma unroll
                for (int rr = 0; rr < 4; ++rr) {
                    int row = m * 16 + ((lane >> 4) << 2) + rr;
                    float h = acc[m][n][rr] + bb;
                    h1G[(size_t)(e0 + row) * 512 + col] = (bf16)h;
                    if (e0 + row < E) { s += h; q += h * h; }
                }
            s += __shfl_xor(s, 16); s += __shfl_xor(s, 32);
            q += __shfl_xor(q, 16); q += __shfl_xor(q, 32);
            if (lane < 16) { atomicAdd(&sum1[col], s); atomicAdd(&sq1[col], q); }
        }
    }
}

// B (tiers 1/2): [gather | pair load] -> GEMM1 -> bn1 -> GEMM2 -> h2 bf16 + stats2
template <int FROMPAIR>
__global__ __launch_bounds__(256, 2)
void k_mlpB12(const bf16* __restrict__ xb2B, const int* __restrict__ ei, const float* __restrict__ ef,
              const bf16* __restrict__ pairG,
              const bf16* __restrict__ W1T, const float* __restrict__ b1,
              const bf16* __restrict__ W2T, const float* __restrict__ b2,
              const float* __restrict__ scale1, const float* __restrict__ shift1,
              float* __restrict__ sum2, float* __restrict__ sq2,
              bf16* __restrict__ h2G, int E) {
    __shared__ char smem[40960 + 32768];
    char* P = smem;
    char* Q = smem + 40960;
    const int tid = threadIdx.x, lane = tid & 63, w = tid >> 6;
    const int e0 = blockIdx.x * 64;

    if (FROMPAIR) stage_pair_glb(P, pairG, e0, tid);
    else          stage_gather<0>(P, xb2B, ei, ei + E, ef, nullptr, e0, E, tid);
    __syncthreads();

    f32x4 acc2[4][4];
    gemm12(P, Q, W1T, b1, W2T, scale1, shift1, w, lane, acc2);

    const int cb2 = w * 64;
    #pragma unroll
    for (int n = 0; n < 4; ++n) {
        int col = cb2 + n * 16 + (lane & 15);
        float bb = b2[col];
        float s = 0.f, q = 0.f;
        #pragma unroll
        for (int m = 0; m < 4; ++m)
            #pragma unroll
            for (int rr = 0; rr < 4; ++rr) {
                int row = m * 16 + ((lane >> 4) << 2) + rr;
                float h = acc2[m][n][rr] + bb;
                h2G[(size_t)(e0 + row) * 256 + col] = (bf16)h;
                if (e0 + row < E) { s += h; q += h * h; }
            }
        s += __shfl_xor(s, 16); s += __shfl_xor(s, 32);
        q += __shfl_xor(q, 16); q += __shfl_xor(q, 32);
        if (lane < 16) { atomicAdd(&sum2[col], s); atomicAdd(&sq2[col], q); }
    }
}

// B (tier 3): h1 -> bn1 during staging -> GEMM2 -> h2 bf16 + stats2.  32 KB LDS.
__global__ __launch_bounds__(256, 3)
void k_mlpB2(const bf16* __restrict__ h1G,
             const bf16* __restrict__ W2T, const float* __restrict__ b2,
             const float* __restrict__ scale1, const float* __restrict__ shift1,
             float* __restrict__ sum2, float* __restrict__ sq2,
             bf16* __restrict__ h2G, int E) {
    __shared__ char Q[32768];
    const int tid = threadIdx.x, lane = tid & 63, w = tid >> 6;
    const int e0 = blockIdx.x * 64;

    f32x4 acc2[4][4];
    #pragma unroll
    for (int m = 0; m < 4; ++m)
        #pragma unroll
        for (int n = 0; n < 4; ++n) acc2[m][n] = (f32x4){0.f, 0.f, 0.f, 0.f};

    #pragma unroll
    for (int half = 0; half < 2; ++half) {
        stage_bn_half(Q, h1G, 512, half * 256, scale1, shift1, e0, tid);
        __syncthreads();
        gemm2_half(Q, W2T, w, lane, half * 256, acc2);
        __syncthreads();
    }

    const int cb2 = w * 64;
    #pragma unroll
    for (int n = 0; n < 4; ++n) {
        int col = cb2 + n * 16 + (lane & 15);
        float bb = b2[col];
        float s = 0.f, q = 0.f;
        #pragma unroll
        for (int m = 0; m < 4; ++m)
            #pragma unroll
            for (int rr = 0; rr < 4; ++rr) {
                int row = m * 16 + ((lane >> 4) << 2) + rr;
                float h = acc2[m][n][rr] + bb;
                h2G[(size_t)(e0 + row) * 256 + col] = (bf16)h;
                if (e0 + row < E) { s += h; q += h * h; }
            }
        s += __shfl_xor(s, 16); s += __shfl_xor(s, 32);
        q += __shfl_xor(q, 16); q += __shfl_xor(q, 32);
        if (lane < 16) { atomicAdd(&sum2[col], s); atomicAdd(&sq2[col], q); }
    }
}

// C (all tiers): h2 -> bn2 during staging -> GEMM3..6 -> out.  32 KB LDS.
__global__ __launch_bounds__(256, 4)
void k_mlpC2(const bf16* __restrict__ h2G,
             const bf16* __restrict__ W3T, const float* __restrict__ b3,
             const bf16* __restrict__ W4T, const float* __restrict__ b4,
             const bf16* __restrict__ W5T, const float* __restrict__ b5,
             const float* __restrict__ W6, const float* __restrict__ b6,
             const float* __restrict__ scale2, const float* __restrict__ shift2,
             float* __restrict__ out, int E) {
    __shared__ char Q[32768];
    const int tid = threadIdx.x, lane = tid & 63, w = tid >> 6;
    const int e0 = blockIdx.x * 64;

    stage_bn_half(Q, h2G, 256, 0, scale2, shift2, e0, tid);
    __syncthreads();

    mlp_tail(Q, W3T, b3, W4T, b4, W5T, b5, W6, b6, out, E, e0, tid, lane, w);
}

// ---------------- T0 fallback: fused edge MLP (3 gather passes, proven R1) ----------------
template <int PASS>
__global__ __launch_bounds__(256, 2)
void k_mlp(const float* __restrict__ x, const int* __restrict__ ei, const float* __restrict__ ef,
           const bf16* __restrict__ W1T, const float* __restrict__ b1,
           const bf16* __restrict__ W2T, const float* __restrict__ b2,
           const bf16* __restrict__ W3T, const float* __restrict__ b3,
           const bf16* __restrict__ W4T, const float* __restrict__ b4,
           const bf16* __restrict__ W5T, const float* __restrict__ b5,
           const float* __restrict__ W6, const float* __restrict__ b6,
           const float* __restrict__ scale1, const float* __restrict__ shift1,
           const float* __restrict__ scale2, const float* __restrict__ shift2,
           float* __restrict__ sum1, float* __restrict__ sq1,
           float* __restrict__ sum2, float* __restrict__ sq2,
           float* __restrict__ out, int E) {
    __shared__ char smem[65536];
    const int tid = threadIdx.x, lane = tid & 63, w = tid >> 6;
    const int e0 = blockIdx.x * 64;
    const int* src = ei;
    const int* dst = ei + E;

    for (int it = tid; it < 64 * 40; it += 256) {
        int r = it / 40, c = it - r * 40;
        int ge = e0 + r;
        float4 fa = {0, 0, 0, 0}, fb = {0, 0, 0, 0};
        if (ge < E) {
            int base = c * 8;
            const float* p;
            if (base < 128)      p = x + (size_t)src[ge] * 128 + base;
            else if (base < 256) p = x + (size_t)dst[ge] * 128 + (base - 128);
            else                 p = ef + (size_t)ge * 64 + (base - 256);
            fa = *(const float4*)p;
            fb = *(const float4*)(p + 4);
        }
        bf16x8 v = to_bf16x8(fa, fb);
        *(bf16x8*)(smem + r * 640 + ((c * 16) ^ ((r & 7) << 4))) = v;
    }
    __syncthreads();

    f32x4 acc[4][8];
    run_gemm1(smem, W1T, w, lane, acc);
    const int cb = w * 128;

    if (PASS == 0) {
        #pragma unroll
        for (int n = 0; n < 8; ++n) {
            int col = cb + n * 16 + (lane & 15);
            float bb = b1[col];
            float s = 0.f, q = 0.f;
            #pragma unroll
            for (int m = 0; m < 4; ++m)
                #pragma unroll
                for (int rr = 0; rr < 4; ++rr) {
                    int row = m * 16 + ((lane >> 4) << 2) + rr;
                    if (e0 + row < E) {
                        float h = acc[m][n][rr] + bb;
                        s += h; q += h * h;
                    }
                }
            s += __shfl_xor(s, 16); s += __shfl_xor(s, 32);
            q += __shfl_xor(q, 16); q += __shfl_xor(q, 32);
            if (lane < 16) { atomicAdd(&sum1[col], s); atomicAdd(&sq1[col], q); }
        }
        return;
    }

    __syncthreads();
    #pragma unroll
    for (int n = 0; n < 8; ++n) {
        int col = cb + n * 16 + (lane & 15);
        float bb = b1[col], sc = scale1[col], sh = shift1[col];
        #pragma unroll
        for (int m = 0; m < 4; ++m)
            #pragma unroll
            for (int rr = 0; rr < 4; ++rr) {
                int row = m * 16 + ((lane >> 4) << 2) + rr;
                float a = fmaxf(fmaf(acc[m][n][rr] + bb, sc, sh), 0.f);
                *(bf16*)(smem + row * 1024 + ((col * 2) ^ ((row & 7) << 4))) = (bf16)a;
            }
    }
    __syncthreads();

    f32x4 acc2[4][4];
    #pragma unroll
    for (int m = 0; m < 4; ++m)
        #pragma unroll
        for (int n = 0; n < 4; ++n) acc2[m][n] = (f32x4){0.f, 0.f, 0.f, 0.f};
    #pragma unroll 2
    for (int ks = 0; ks < 16; ++ks) {
        bf16x8 a[4];
        #pragma unroll
        for (int m = 0; m < 4; ++m) a[m] = lds_afrag(smem, 512, m * 16, ks * 32, lane);
        #pragma unroll
        for (int n = 0; n < 4; ++n) {
            bf16x8 b = glb_bfrag(W2T, 512, w * 64 + n * 16, ks * 32, lane);
            #pragma unroll
            for (int m = 0; m < 4; ++m) acc2[m][n] = MFMA16(a[m], b, acc2[m][n]);
        }
    }
    const int cb2 = w * 64;

    if (PASS == 1) {
        #pragma unroll
        for (int n = 0; n < 4; ++n) {
            int col = cb2 + n * 16 + (lane & 15);
            float bb = b2[col];
            float s = 0.f, q = 0.f;
            #pragma unroll
            for (int m = 0; m < 4; ++m)
                #pragma unroll
                for (int rr = 0; rr < 4; ++rr) {
                    int row = m * 16 + ((lane >> 4) << 2) + rr;
                    if (e0 + row < E) {
                        float h = acc2[m][n][rr] + bb;
                        s += h; q += h * h;
                    }
                }
            s += __shfl_xor(s, 16); s += __shfl_xor(s, 32);
            q += __shfl_xor(q, 16); q += __shfl_xor(q, 32);
            if (lane < 16) { atomicAdd(&sum2[col], s); atomicAdd(&sq2[col], q); }
        }
        return;
    }

    __syncthreads();
    if (tid < 32) *(float*)(smem + 49152 + tid * 4) = W6[tid];
    #pragma unroll
    for (int n = 0; n < 4; ++n) {
        int col = cb2 + n * 16 + (lane & 15);
        float bb = b2[col], sc = scale2[col], sh = shift2[col];
        #pragma unroll
        for (int m = 0; m < 4; ++m)
            #pragma unroll
            for (int rr = 0; rr < 4; ++rr) {
                int row = m * 16 + ((lane >> 4) << 2) + rr;
                float a = fmaxf(fmaf(acc2[m][n][rr] + bb, sc, sh), 0.f);
                *(bf16*)(smem + row * 512 + ((col * 2) ^ ((row & 7) << 4))) = (bf16)a;
            }
    }
    __syncthreads();

    f32x4 acc3[4][2];
    #pragma unroll
    for (int m = 0; m < 4; ++m)
        #pragma unroll
        for (int n = 0; n < 2; ++n) acc3[m][n] = (f32x4){0.f, 0.f, 0.f, 0.f};
    for (int ks = 0; ks < 8; ++ks) {
        bf16x8 a[4];
        #pragma unroll
        for (int m = 0; m < 4; ++m) a[m] = lds_afrag(smem, 256, m * 16, ks * 32, lane);
        #pragma unroll
        for (int n = 0; n < 2; ++n) {
            bf16x8 b = glb_bfrag(W3T, 256, w * 32 + n * 16, ks * 32, lane);
            #pragma unroll
            for (int m = 0; m < 4; ++m) acc3[m][n] = MFMA16(a[m], b, acc3[m][n]);
        }
    }
    __syncthreads();
    #pragma unroll
    for (int n = 0; n < 2; ++n) {
        int col = w * 32 + n * 16 + (lane & 15);
        float bb = b3[col];
        #pragma unroll
        for (int m = 0; m < 4; ++m)
            #pragma unroll
            for (int rr = 0; rr < 4; ++rr) {
                int row = m * 16 + ((lane >> 4) << 2) + rr;
                float a = fmaxf(acc3[m][n][rr] + bb, 0.f);
                *(bf16*)(smem + row * 256 + ((col * 2) ^ ((row & 7) << 4))) = (bf16)a;
            }
    }
    __syncthreads();

    f32x4 acc4[4];
    #pragma unroll
    for (int m = 0; m < 4; ++m) acc4[m] = (f32x4){0.f, 0.f, 0.f, 0.f};
    for (int ks = 0; ks < 4; ++ks) {
        bf16x8 a[4];
        #pragma unroll
        for (int m = 0; m < 4; ++m) a[m] = lds_afrag(smem, 128, m * 16, ks * 32, lane);
        bf16x8 b = glb_bfrag(W4T, 128, w * 16, ks * 32, lane);
        #pragma unroll
        for (int m = 0; m < 4; ++m) acc4[m] = MFMA16(a[m], b, acc4[m]);
    }
    __syncthreads();
    {
        int col = w * 16 + (lane & 15);
        float bb = b4[col];
        #pragma unroll
        for (int m = 0; m < 4; ++m)
            #pragma unroll
            for (int rr = 0; rr < 4; ++rr) {
                int row = m * 16 + ((lane >> 4) << 2) + rr;
                float a = fmaxf(acc4[m][rr] + bb, 0.f);
                *(bf16*)(smem + row * 128 + ((col * 2) ^ ((row & 7) << 4))) = (bf16)a;
            }
    }
    __syncthreads();

    if (w < 2) {
        f32x4 acc5[4];
        #pragma unroll
        for (int m = 0; m < 4; ++m) acc5[m] = (f32x4){0.f, 0.f, 0.f, 0.f};
        for (int ks = 0; ks < 2; ++ks) {
            bf16x8 a[4];
            #pragma unroll
            for (int m = 0; m < 4; ++m) a[m] = lds_afrag(smem, 64, m * 16, ks * 32, lane);
            bf16x8 b = glb_bfrag(W5T, 64, w * 16, ks * 32, lane);
            #pragma unroll
            for (int m = 0; m < 4; ++m) acc5[m] = MFMA16(a[m], b, acc5[m]);
        }
        int col = w * 16 + (lane & 15);
        float bb = b5[col];
        float* a5f = (float*)(smem + 16384);
        #pragma unroll
        for (int m = 0; m < 4; ++m)
            #pragma unroll
            for (int rr = 0; rr < 4; ++rr) {
                int row = m * 16 + ((lane >> 4) << 2) + rr;
                a5f[row * 32 + col] = fmaxf(acc5[m][rr] + bb, 0.f);
            }
    }
    __syncthreads();

    if (tid < 64) {
        int ge = e0 + tid;
        if (ge < E) {
            const float* a5f = (const float*)(smem + 16384) + tid * 32;
            const float* w6 = (const float*)(smem + 49152);
            float s = b6[0];
            #pragma unroll
            for (int k = 0; k < 32; ++k) {
                int kk = (k + tid) & 31;
                s = fmaf(a5f[kk], w6[kk], s);
            }
            out[ge] = s;
        }
    }
}

// ---------------- launch ----------------

extern "C" void kernel_launch(void* const* d_in, const int* in_sizes, int n_in,
                              void* d_out, int out_size, void* d_ws, size_t ws_size,
                              hipStream_t stream) {
    const float* x      = (const float*)d_in[0];
    const int*   ei     = (const int*)d_in[1];
    const float* ef     = (const float*)d_in[2];
    const float* W_nb   = (const float*)d_in[4];
    const float* b_nb   = (const float*)d_in[5];
    const float* W_self = (const float*)d_in[6];
    const float* b_self = (const float*)d_in[7];
    const float* W1 = (const float*)d_in[8];  const float* b1 = (const float*)d_in[9];
    const float* W2 = (const float*)d_in[10]; const float* b2 = (const float*)d_in[11];
    const float* W3 = (const float*)d_in[12]; const float* b3 = (const float*)d_in[13];
    const float* W4 = (const float*)d_in[14]; const float* b4 = (const float*)d_in[15];
    const float* W5 = (const float*)d_in[16]; const float* b5 = (const float*)d_in[17];
    const float* W6 = (const float*)d_in[18]; const float* b6 = (const float*)d_in[19];
    const float* g1 = (const float*)d_in[20]; const float* beta1 = (const float*)d_in[21];
    const float* g2 = (const float*)d_in[22]; const float* beta2 = (const float*)d_in[23];

    const int N = in_sizes[0] / 128;
    const int E = in_sizes[1] / 2;
    const int mlpGrid = (E + 63) / 64;
    const size_t Epad = (size_t)mlpGrid * 64;

    char* ws = (char*)d_ws;
    size_t off = 0;
    auto alloc = [&](size_t bytes) {
        size_t o = off;
        off = (off + bytes + 255) & ~(size_t)255;
        return o;
    };
    // --- permanent region ---
    size_t oSum1 = alloc(512 * 4), oSq1 = alloc(512 * 4);
    size_t oSum2 = alloc(256 * 4), oSq2 = alloc(256 * 4);
    size_t zeroEnd = off;
    size_t oScale1 = alloc(512 * 4), oShift1 = alloc(512 * 4);
    size_t oScale2 = alloc(256 * 4), oShift2 = alloc(256 * 4);
    size_t oWcat = alloc(128 * 320 * 2);
    size_t oW1T = alloc((size_t)512 * 320 * 2);
    size_t oW2T = alloc((size_t)256 * 512 * 2);
    size_t oW3T = alloc((size_t)128 * 256 * 2);
    size_t oW4T = alloc((size_t)64 * 128 * 2);
    size_t oW5T = alloc((size_t)32 * 64 * 2);
    size_t oXb2B = alloc((size_t)N * 128 * 2);
    size_t permEnd = off;
    // --- conv scratch (dead once MLP phase starts) ---
    size_t oDeg = alloc((size_t)N * 4);
    size_t oCur = alloc((size_t)N * 4);
    size_t oOff = alloc((size_t)(N + 1) * 4);
    size_t oInv = alloc((size_t)N * 4);
    size_t oEid = alloc((size_t)E * 4);
    size_t oSm  = alloc((size_t)N * 192 * 4);
    size_t oXb1 = alloc((size_t)N * 128 * 4);
    size_t oXb2 = alloc((size_t)N * 128 * 4);
    size_t convEnd = off;

    auto align256 = [](size_t v) { return (v + 255) & ~(size_t)255; };
    // --- MLP buffers overlay the conv scratch (all start at permEnd) ---
    // tier 3: h1 + h2
    size_t oH1 = align256(permEnd);
    size_t oH2_t3 = align256(oH1 + Epad * 512 * 2);
    size_t m3End = align256(oH2_t3 + Epad * 256 * 2);
    // tier 2: pair + h2
    size_t oPair = align256(permEnd);
    size_t oH2_t2 = align256(oPair + Epad * 320 * 2);
    size_t m2End = align256(oH2_t2 + Epad * 256 * 2);
    // tier 1: h2 only
    size_t oH2_t1 = align256(permEnd);
    size_t m1End = align256(oH2_t1 + Epad * 256 * 2);

    auto fits = [&](size_t mEnd) { return ws_size >= (mEnd > convEnd ? mEnd : convEnd); };
    int mode = fits(m3End) ? 3 : fits(m2End) ? 2 : fits(m1End) ? 1 : (ws_size >= convEnd) ? 0 : -1;
    if (mode < 0) return;

    float* sum1 = (float*)(ws + oSum1); float* sq1 = (float*)(ws + oSq1);
    float* sum2 = (float*)(ws + oSum2); float* sq2 = (float*)(ws + oSq2);
    float* scale1 = (float*)(ws + oScale1); float* shift1 = (float*)(ws + oShift1);
    float* scale2 = (float*)(ws + oScale2); float* shift2 = (float*)(ws + oShift2);
    bf16* WcatT = (bf16*)(ws + oWcat);
    bf16* W1T = (bf16*)(ws + oW1T);
    bf16* W2T = (bf16*)(ws + oW2T);
    bf16* W3T = (bf16*)(ws + oW3T);
    bf16* W4T = (bf16*)(ws + oW4T);
    bf16* W5T = (bf16*)(ws + oW5T);
    bf16* xb2B = (bf16*)(ws + oXb2B);
    float* deg = (float*)(ws + oDeg);
    unsigned* cursor = (unsigned*)(ws + oCur);
    unsigned* offsets = (unsigned*)(ws + oOff);
    float* invdeg = (float*)(ws + oInv);
    unsigned* eid = (unsigned*)(ws + oEid);
    float* sm  = (float*)(ws + oSm);
    float* xb1 = (float*)(ws + oXb1);
    float* xb2 = (float*)(ws + oXb2);
    bf16* h1G = (bf16*)(ws + oH1);
    bf16* pairG = (bf16*)(ws + oPair);
    bf16* h2G = (bf16*)(ws + (mode == 3 ? oH2_t3 : mode == 2 ? oH2_t2 : oH2_t1));

    hipMemsetAsync(ws, 0, zeroEnd, stream);                    // stats accumulators
    hipMemsetAsync(ws + oDeg, 0, oOff - oDeg, stream);         // deg + cursor

    k_transpose<<<(128 * 128 + 255) / 256, 256, 0, stream>>>(W_self, WcatT, 128, 128, 320, 0);
    k_transpose<<<(192 * 128 + 255) / 256, 256, 0, stream>>>(W_nb, WcatT, 192, 128, 320, 128);
    k_transpose<<<(320 * 512 + 255) / 256, 256, 0, stream>>>(W1, W1T, 320, 512, 320, 0);
    k_transpose<<<(512 * 256 + 255) / 256, 256, 0, stream>>>(W2, W2T, 512, 256, 512, 0);
    k_transpose<<<(256 * 128 + 255) / 256, 256, 0, stream>>>(W3, W3T, 256, 128, 256, 0);
    k_transpose<<<(128 * 64 + 255) / 256, 256, 0, stream>>>(W4, W4T, 128, 64, 128, 0);
    k_transpose<<<(64 * 32 + 255) / 256, 256, 0, stream>>>(W5, W5T, 64, 32, 64, 0);

    const int* dst = ei + E;
    k_deg<<<(E + 255) / 256, 256, 0, stream>>>(dst, deg, E);
    k_scan<<<1, 1024, 0, stream>>>(deg, offsets, invdeg, N);
    k_scatter<<<(E + 255) / 256, 256, 0, stream>>>(dst, offsets, cursor, eid, E);

    k_agg<<<(N + 15) / 16, 256, 0, stream>>>(x, ef, ei, offsets, invdeg, eid, sm, N);
    k_nodegemm<0><<<(N + 63) / 64, 256, 0, stream>>>(x, sm, WcatT, b_self, b_nb, offsets, xb1, nullptr, N);
    k_agg<<<(N + 15) / 16, 256, 0, stream>>>(xb1, ef, ei, offsets, invdeg, eid, sm, N);

    const float invE = 1.0f / (float)E;
    if (mode >= 1) {
        k_nodegemm<1><<<(N + 63) / 64, 256, 0, stream>>>(xb1, sm, WcatT, b_self, b_nb, offsets, nullptr, xb2B, N);
        if (mode == 3) {
            k_mlpA2<<<mlpGrid, 256, 0, stream>>>(xb2B, ei, ef, W1T, b1, sum1, sq1, h1G, E);
            k_finalize<<<2, 256, 0, stream>>>(sum1, sq1, g1, beta1, scale1, shift1, 512, invE);
            k_mlpB2<<<mlpGrid, 256, 0, stream>>>(h1G, W2T, b2, scale1, shift1, sum2, sq2, h2G, E);
        } else if (mode == 2) {
            k_mlpA<1><<<mlpGrid, 256, 0, stream>>>(xb2B, ei, ef, W1T, b1, sum1, sq1, pairG, E);
            k_finalize<<<2, 256, 0, stream>>>(sum1, sq1, g1, beta1, scale1, shift1, 512, invE);
            k_mlpB12<1><<<mlpGrid, 256, 0, stream>>>(xb2B, ei, ef, pairG, W1T, b1, W2T, b2,
                                                     scale1, shift1, sum2, sq2, h2G, E);
        } else {
            k_mlpA<0><<<mlpGrid, 256, 0, stream>>>(xb2B, ei, ef, W1T, b1, sum1, sq1, nullptr, E);
            k_finalize<<<2, 256, 0, stream>>>(sum1, sq1, g1, beta1, scale1, shift1, 512, invE);
            k_mlpB12<0><<<mlpGrid, 256, 0, stream>>>(xb2B, ei, ef, nullptr, W1T, b1, W2T, b2,
                                                     scale1, shift1, sum2, sq2, h2G, E);
        }
        k_finalize<<<1, 256, 0, stream>>>(sum2, sq2, g2, beta2, scale2, shift2, 256, invE);
        k_mlpC2<<<mlpGrid, 256, 0, stream>>>(h2G, W3T, b3, W4T, b4, W5T, b5, W6, b6,
                                             scale2, shift2, (float*)d_out, E);
    } else {
        k_nodegemm<0><<<(N + 63) / 64, 256, 0, stream>>>(xb1, sm, WcatT, b_self, b_nb, offsets, xb2, nullptr, N);
        k_mlp<0><<<mlpGrid, 256, 0, stream>>>(xb2, ei, ef, W1T, b1, W2T, b2, W3T, b3, W4T, b4,
                                              W5T, b5, W6, b6, scale1, shift1, scale2, shift2,
                                              sum1, sq1, sum2, sq2, (float*)d_out, E);
        k_finalize<<<2, 256, 0, stream>>>(sum1, sq1, g1, beta1, scale1, shift1, 512, invE);
        k_mlp<1><<<mlpGrid, 256, 0, stream>>>(xb2, ei, ef, W1T, b1, W2T, b2, W3T, b3, W4T, b4,
                                              W5T, b5, W6, b6, scale1, shift1, scale2, shift2,
                                              sum1, sq1, sum2, sq2, (float*)d_out, E);
        k_finalize<<<1, 256, 0, stream>>>(sum2, sq2, g2, beta2, scale2, shift2, 256, invE);
        k_mlp<2><<<mlpGrid, 256, 0, stream>>>(xb2, ei, ef, W1T, b1, W2T, b2, W3T, b3, W4T, b4,
                                              W5T, b5, W6, b6, scale1, shift1, scale2, shift2,
                                              sum1, sq1, sum2, sq2, (float*)d_out, E);
    }
}